// Round 9
// baseline (379.436 us; speedup 1.0000x reference)
//
#include <hip/hip_runtime.h>
#include <hip/hip_bf16.h>
#include <math.h>

// Problem constants
#define D_   1024
#define HD_  64
#define NH_  16
#define H_   16
#define KH_  8
#define NT_  128      // tokens per chunk (N)
#define E_   4096
#define RE_  4
#define DE_  4
#define ET_  16
#define S_   2048
#define T_   2048
#define BC_  16
#define EPS_ 1e-5f

typedef short s16x8 __attribute__((ext_vector_type(8)));
typedef float f32x4 __attribute__((ext_vector_type(4)));

__device__ __forceinline__ unsigned short f2bf(float f) {
    union { float f; unsigned int u; } v; v.f = f;
    unsigned int r = (v.u + 0x7fffu + ((v.u >> 16) & 1u)) >> 16;  // RNE
    return (unsigned short)r;
}

// async global->LDS, 16B per lane; LDS dest is wave-uniform base + lane*16.
#define GLOAD16(gp, lp) __builtin_amdgcn_global_load_lds(                      \
    (__attribute__((address_space(1))) void*)(gp),                             \
    (__attribute__((address_space(3))) void*)(lp), 16, 0, 0)

// ---------------------------------------------------------------------------
// Mega-preprocess (input-only dependencies), one launch:
//   [0,2048):     rmsnorm(x_input) -> xnb bf16
//   [2048,5120):  convt attn_w (1024x3072) -> wqkvT [3072][1024] bf16
//   [5120,6144):  convt attn_out_w (1024x1024) -> woutT [1024][1024] bf16
//   [6144,14336): keys compact: block (kh,d) reads row keys[kh][d][:]
//                 COALESCED (16KB), LDS-stages, picks the 256 indexed cols ->
//                 tmpT[kh][d][pair] bf16.
// ---------------------------------------------------------------------------
__global__ __launch_bounds__(256) void preprocess_kernel(
    const float* __restrict__ x, const float* __restrict__ attn_norm_w,
    unsigned short* __restrict__ xnb,
    const float* __restrict__ attn_w, unsigned short* __restrict__ wqkvT,
    const float* __restrict__ attn_out_w, unsigned short* __restrict__ woutT,
    const float* __restrict__ keys, const int* __restrict__ indices,
    unsigned short* __restrict__ tmpT)
{
    __shared__ float tile[32][33];
    __shared__ float sred[4];
    __shared__ float rowbuf[E_];
    int bid = blockIdx.x, tid = threadIdx.x;

    if (bid < 2048) {
        // ---- rmsnorm -> bf16 ----
        int row = bid;
        float4 v = ((const float4*)(x + (size_t)row * D_))[tid];
        float ss = v.x*v.x + v.y*v.y + v.z*v.z + v.w*v.w;
#pragma unroll
        for (int off = 32; off > 0; off >>= 1) ss += __shfl_xor(ss, off);
        if ((tid & 63) == 0) sred[tid >> 6] = ss;
        __syncthreads();
        float tot = sred[0] + sred[1] + sred[2] + sred[3];
        float scale = rsqrtf(tot * (1.0f / D_) + EPS_);
        float4 wv = ((const float4*)attn_norm_w)[tid];
        ushort4 o;
        o.x = f2bf(v.x * scale * wv.x);
        o.y = f2bf(v.y * scale * wv.y);
        o.z = f2bf(v.z * scale * wv.z);
        o.w = f2bf(v.w * scale * wv.w);
        *(ushort4*)(xnb + (size_t)row * D_ + tid * 4) = o;
    } else if (bid < 6144) {
        // ---- convert + transpose weight ----
        const float* src; unsigned short* dst; int R, Ncols, bx, by;
        if (bid < 5120) {
            int cid = bid - 2048;
            src = attn_w; dst = wqkvT; R = D_; Ncols = 3 * D_;
            bx = (cid % 96) * 32; by = (cid / 96) * 32;
        } else {
            int cid = bid - 5120;
            src = attn_out_w; dst = woutT; R = D_; Ncols = D_;
            bx = (cid & 31) * 32; by = (cid >> 5) * 32;
        }
        int tx = tid & 31, ty = tid >> 5;
#pragma unroll
        for (int rr = 0; rr < 32; rr += 8)
            tile[ty + rr][tx] = src[(size_t)(by + ty + rr) * Ncols + bx + tx];
        __syncthreads();
#pragma unroll
        for (int rr = 0; rr < 32; rr += 8)
            dst[(size_t)(bx + ty + rr) * R + by + tx] = f2bf(tile[tx][ty + rr]);
    } else {
        // ---- keys compact: coalesced row read + LDS column pick ----
        int id = bid - 6144;          // 0..8191
        int kh = id >> 10;            // /D_
        int d  = id & (D_ - 1);
        const float* rowp = keys + ((size_t)kh * D_ + d) * E_;
#pragma unroll
        for (int pass = 0; pass < 4; pass++)
            ((float4*)rowbuf)[tid + pass * 256] =
                ((const float4*)rowp)[tid + pass * 256];
        __syncthreads();
        int idx = indices[tid];       // pair = tid (256 pairs)
        tmpT[((size_t)kh * D_ + d) * 256 + tid] = f2bf(rowbuf[idx]);
    }
}

// ---------------------------------------------------------------------------
// keys transpose: tmpT [kh][d][pair] -> kgath[(pair>>4)*128+(pair&15)*8+kh][d]
// ---------------------------------------------------------------------------
__global__ __launch_bounds__(256) void transpose_keys_kernel(
    const unsigned short* __restrict__ tmpT, unsigned short* __restrict__ kgath)
{
    __shared__ unsigned short tile[32][34];
    int p0 = blockIdx.x * 32;     // pair tile (8)
    int d0 = blockIdx.y * 32;     // d tile (32)
    int kh = blockIdx.z;          // (8)
    int tx = threadIdx.x & 31, ty = threadIdx.x >> 5;
#pragma unroll
    for (int rr = 0; rr < 32; rr += 8)
        tile[ty + rr][tx] = tmpT[((size_t)kh * D_ + d0 + ty + rr) * 256 + p0 + tx];
    __syncthreads();
#pragma unroll
    for (int rr = 0; rr < 32; rr += 8) {
        int p = p0 + ty + rr;
        int n = (p >> 4) * 128 + (p & 15) * 8 + kh;
        kgath[(size_t)n * D_ + d0 + tx] = tile[tx][ty + rr];
    }
}

// rmsnorm dual: fp32 out + bf16 out
__global__ __launch_bounds__(256) void rmsnorm_dual_kernel(
    const float* __restrict__ x, const float* __restrict__ w,
    float* __restrict__ out, unsigned short* __restrict__ outb)
{
    int row = blockIdx.x, tid = threadIdx.x;
    __shared__ float sred[4];
    float4 v = ((const float4*)(x + (size_t)row * D_))[tid];
    float ss = v.x*v.x + v.y*v.y + v.z*v.z + v.w*v.w;
#pragma unroll
    for (int off = 32; off > 0; off >>= 1) ss += __shfl_xor(ss, off);
    if ((tid & 63) == 0) sred[tid >> 6] = ss;
    __syncthreads();
    float tot = sred[0] + sred[1] + sred[2] + sred[3];
    float scale = rsqrtf(tot * (1.0f / D_) + EPS_);
    float4 wv = ((const float4*)w)[tid];
    float4 o;
    o.x = v.x * scale * wv.x;
    o.y = v.y * scale * wv.y;
    o.z = v.z * scale * wv.z;
    o.w = v.w * scale * wv.w;
    ((float4*)(out + (size_t)row * D_))[tid] = o;
    ushort4 ob;
    ob.x = f2bf(o.x); ob.y = f2bf(o.y); ob.z = f2bf(o.z); ob.w = f2bf(o.w);
    *(ushort4*)(outb + (size_t)row * D_ + tid * 4) = ob;
}

// ---------------------------------------------------------------------------
// MFMA GEMM: C[M,N] fp32 = A[M,K] bf16 @ Bt[N,K] bf16 (+ res fp32)
// ---------------------------------------------------------------------------
template <int WITH_RES>
__global__ __launch_bounds__(256) void mfma_gemm_kernel(
    const unsigned short* __restrict__ A, const unsigned short* __restrict__ Bt,
    const float* __restrict__ res, float* __restrict__ C,
    int M, int N, int K)
{
    __shared__ __align__(16) short As[128][32];
    __shared__ __align__(16) short Bs[128][32];
    int tid = threadIdx.x;
    int wave = tid >> 6, lane = tid & 63;
    int ml = lane & 15, q = lane >> 4;
    int wr = wave >> 1, wc = wave & 1;
    int bm = blockIdx.y * 128, bn = blockIdx.x * 128;
    int srow = tid >> 2;           // 0..63
    int scol = (tid & 3) * 8;      // shorts

    f32x4 acc[4][4];
#pragma unroll
    for (int i = 0; i < 4; i++)
#pragma unroll
        for (int j = 0; j < 4; j++) acc[i][j] = (f32x4){0.f, 0.f, 0.f, 0.f};

    const unsigned short* Ap = A  + (size_t)(bm + srow) * K + scol;
    const unsigned short* Bp = Bt + (size_t)(bn + srow) * K + scol;
    short* ldsA0 = &As[wave * 16][0];
    short* ldsA1 = &As[64 + wave * 16][0];
    short* ldsB0 = &Bs[wave * 16][0];
    short* ldsB1 = &Bs[64 + wave * 16][0];

    for (int k0 = 0; k0 < K; k0 += 32) {
        __syncthreads();
        GLOAD16(Ap + k0, ldsA0);
        GLOAD16(Ap + (size_t)64 * K + k0, ldsA1);
        GLOAD16(Bp + k0, ldsB0);
        GLOAD16(Bp + (size_t)64 * K + k0, ldsB1);
        __syncthreads();

        s16x8 af[4], bf[4];
#pragma unroll
        for (int i = 0; i < 4; i++)
            af[i] = *(const s16x8*)(&As[wr * 64 + i * 16 + ml][q * 8]);
#pragma unroll
        for (int j = 0; j < 4; j++)
            bf[j] = *(const s16x8*)(&Bs[wc * 64 + j * 16 + ml][q * 8]);
#pragma unroll
        for (int i = 0; i < 4; i++)
#pragma unroll
            for (int j = 0; j < 4; j++)
                acc[i][j] = __builtin_amdgcn_mfma_f32_16x16x32_bf16(
                    af[i], bf[j], acc[i][j], 0, 0, 0);
    }

#pragma unroll
    for (int i = 0; i < 4; i++) {
#pragma unroll
        for (int j = 0; j < 4; j++) {
            int col = bn + wc * 64 + j * 16 + ml;
#pragma unroll
            for (int r = 0; r < 4; r++) {
                int row = bm + wr * 64 + i * 16 + q * 4 + r;
                float v = acc[i][j][r];
                if (WITH_RES) v += res[(size_t)row * N + col];
                C[(size_t)row * N + col] = v;
            }
        }
    }
}

// ---------------------------------------------------------------------------
// Fused QKV GEMM: qkv = xnb @ wqkvT^T with epilogue l2norm + rope + split.
// V written directly transposed (vhT[h][d][s]).
//   grid (24, 16); blockIdx.x: [0,8)=q, [8,16)=k, [16,24)=v.
// ---------------------------------------------------------------------------
__global__ __launch_bounds__(256) void mfma_gemm_qkv_kernel(
    const unsigned short* __restrict__ A, const unsigned short* __restrict__ Bt,
    unsigned short* __restrict__ qh, unsigned short* __restrict__ khb,
    unsigned short* __restrict__ vhT)
{
    const int K = D_;
    __shared__ __align__(16) short As[128][32];
    __shared__ __align__(16) short Bs[128][32];
    int tid = threadIdx.x;
    int wave = tid >> 6, lane = tid & 63;
    int ml = lane & 15, q = lane >> 4;
    int wr = wave >> 1, wc = wave & 1;
    int bm = blockIdx.y * 128, bn = blockIdx.x * 128;
    int srow = tid >> 2;
    int scol = (tid & 3) * 8;

    f32x4 acc[4][4];
#pragma unroll
    for (int i = 0; i < 4; i++)
#pragma unroll
        for (int j = 0; j < 4; j++) acc[i][j] = (f32x4){0.f, 0.f, 0.f, 0.f};

    const unsigned short* Ap = A  + (size_t)(bm + srow) * K + scol;
    const unsigned short* Bp = Bt + (size_t)(bn + srow) * K + scol;
    short* ldsA0 = &As[wave * 16][0];
    short* ldsA1 = &As[64 + wave * 16][0];
    short* ldsB0 = &Bs[wave * 16][0];
    short* ldsB1 = &Bs[64 + wave * 16][0];

    for (int k0 = 0; k0 < K; k0 += 32) {
        __syncthreads();
        GLOAD16(Ap + k0, ldsA0);
        GLOAD16(Ap + (size_t)64 * K + k0, ldsA1);
        GLOAD16(Bp + k0, ldsB0);
        GLOAD16(Bp + (size_t)64 * K + k0, ldsB1);
        __syncthreads();

        s16x8 af[4], bf[4];
#pragma unroll
        for (int i = 0; i < 4; i++)
            af[i] = *(const s16x8*)(&As[wr * 64 + i * 16 + ml][q * 8]);
#pragma unroll
        for (int j = 0; j < 4; j++)
            bf[j] = *(const s16x8*)(&Bs[wc * 64 + j * 16 + ml][q * 8]);
#pragma unroll
        for (int i = 0; i < 4; i++)
#pragma unroll
            for (int j = 0; j < 4; j++)
                acc[i][j] = __builtin_amdgcn_mfma_f32_16x16x32_bf16(
                    af[i], bf[j], acc[i][j], 0, 0, 0);
    }

    // ---- epilogue: l2norm + rope + bf16 split write ----
    int sel = blockIdx.x >> 3;                  // 0:q 1:k 2:v
    int h = ((blockIdx.x & 7) << 1) + wc;       // head for this wave
    float qscale = (sel == 0) ? 0.125f : 1.0f;  // fold 1/sqrt(64) into q
    float if0 = exp2f((float)ml * (-13.287712379549449f / 32.0f));
    float if1 = exp2f((float)(16 + ml) * (-13.287712379549449f / 32.0f));

#pragma unroll
    for (int i = 0; i < 4; i++) {
#pragma unroll
        for (int r = 0; r < 4; r++) {
            int row = bm + wr * 64 + i * 16 + q * 4 + r;
            float v0 = acc[i][0][r], v1 = acc[i][1][r];
            float v2 = acc[i][2][r], v3 = acc[i][3][r];
            if (sel < 2) {
                float ss = v0*v0 + v1*v1 + v2*v2 + v3*v3;
#pragma unroll
                for (int off = 1; off < 16; off <<= 1)
                    ss += __shfl_xor(ss, off);
                float inv = qscale / fmaxf(sqrtf(ss), EPS_);
                v0 *= inv; v1 *= inv; v2 *= inv; v3 *= inv;
                float sn0, cs0, sn1, cs1;
                sincosf((float)row * if0, &sn0, &cs0);
                sincosf((float)row * if1, &sn1, &cs1);
                float o0 = v0 * cs0 + v2 * sn0;
                float o2 = v2 * cs0 - v0 * sn0;
                float o1 = v1 * cs1 + v3 * sn1;
                float o3 = v3 * cs1 - v1 * sn1;
                v0 = o0; v1 = o1; v2 = o2; v3 = o3;
                unsigned short* dst = (sel == 0) ? qh : khb;
                size_t base = ((size_t)h * S_ + row) * HD_;
                dst[base +      ml] = f2bf(v0);
                dst[base + 16 + ml] = f2bf(v1);
                dst[base + 32 + ml] = f2bf(v2);
                dst[base + 48 + ml] = f2bf(v3);
            } else {
                // V: write transposed vhT[h][d][row], d = k*16 + ml
                size_t base = ((size_t)h * HD_ + ml) * S_ + row;
                vhT[base            ] = f2bf(v0);
                vhT[base + 16 * S_  ] = f2bf(v1);
                vhT[base + 32 * S_  ] = f2bf(v2);
                vhT[base + 48 * S_  ] = f2bf(v3);
            }
        }
    }
}

// ---------------------------------------------------------------------------
// MFMA bf16 flash attention, split-K x2 over kt (bounded softmax makes the
// split trivially associative: o and l are PURE SUMS — no max merge).
//   1024 blocks = (xcd owns 2 heads; t zigzag; half = even/odd kt subset).
//   Group `half` processes kt ≡ half (mod 2), kt <= t; the causal tile kt==t
//   lands in exactly one half (t mod 2). Partials: opart fp32 + lpart fp32,
//   summed + normalized by flash_combine_kernel.
//   4 blocks/CU -> 2x latency hiding; per-block max iters 32 -> 16.
// ---------------------------------------------------------------------------
#define FS 72   // shorts per LDS row (pad: 144B rows -> 2-way banks, free)
__global__ __launch_bounds__(256) void flash_attn_mfma_kernel(
    const unsigned short* __restrict__ qh, const unsigned short* __restrict__ khb,
    const unsigned short* __restrict__ vhT,
    float* __restrict__ opart, float* __restrict__ lpart)
{
    __shared__ __align__(16) short Ks[2][64][FS];
    __shared__ __align__(16) short Vs[2][64][FS];   // [buf][d][token]
    __shared__ __align__(16) short Ps[4][16][FS];   // per-wave scratch
    int b = blockIdx.x;
    int xcd = b & 7, j = b >> 3;        // j in [0,128)
    int h = 2 * xcd + (j & 1);
    int j2 = j >> 1;                    // [0,64)
    int pp = j2 & 31, half = j2 >> 5;
    int t = (pp < 16) ? pp : (47 - pp); // zigzag: heavy/light pairing per CU
    int tid = threadIdx.x;
    int wq = tid >> 6;
    int lane = tid & 63;
    int ml = lane & 15, quad = lane >> 4;
    int srow = tid >> 2;          // 0..63
    int sc = (tid & 3) * 16;      // 0,16,32,48 (shorts)
    const unsigned short* Qb = qh  + (size_t)h * S_ * HD_;
    const unsigned short* Kb = khb + (size_t)h * S_ * HD_;
    const unsigned short* Vt = vhT + (size_t)h * HD_ * S_;

    int q0 = t * 64;
    int qrow = q0 + wq * 16 + ml;
    s16x8 aq0 = *(const s16x8*)(Qb + (size_t)qrow * HD_ + quad * 8);
    s16x8 aq1 = *(const s16x8*)(Qb + (size_t)qrow * HD_ + 32 + quad * 8);

    float ps[4];                  // per-lane partial row sums
    f32x4 o[4];
#pragma unroll
    for (int r = 0; r < 4; r++) ps[r] = 0.f;
#pragma unroll
    for (int nb = 0; nb < 4; nb++) o[nb] = (f32x4){0.f, 0.f, 0.f, 0.f};

    int4 kr0, kr1, vr0, vr1;      // staging registers
    // prologue: tile `half` -> buf 0 (visibility via iter-0 top barrier)
    {
        const unsigned short* kp = Kb + (size_t)(half * 64 + srow) * HD_ + sc;
        kr0 = *(const int4*)kp; kr1 = *(const int4*)(kp + 8);
        const unsigned short* vp = Vt + (size_t)srow * S_ + half * 64 + sc;
        vr0 = *(const int4*)vp; vr1 = *(const int4*)(vp + 8);
        *(int4*)(&Ks[0][srow][sc]) = kr0; *(int4*)(&Ks[0][srow][sc + 8]) = kr1;
        *(int4*)(&Vs[0][srow][sc]) = vr0; *(int4*)(&Vs[0][srow][sc + 8]) = vr1;
    }

    int cur = 0;
    for (int kt = half; kt <= t; kt += 2) {
        int k0 = kt * 64;
        // issue tile kt+2's global loads early (hides under compute)
        if (kt + 2 <= t) {
            const unsigned short* kp = Kb + (size_t)(k0 + 128 + srow) * HD_ + sc;
            kr0 = *(const int4*)kp; kr1 = *(const int4*)(kp + 8);
            const unsigned short* vp = Vt + (size_t)srow * S_ + k0 + 128 + sc;
            vr0 = *(const int4*)vp; vr1 = *(const int4*)(vp + 8);
        }
        __syncthreads();           // single barrier per iteration

        f32x4 s[4];
#pragma unroll
        for (int nb = 0; nb < 4; nb++) s[nb] = (f32x4){0.f, 0.f, 0.f, 0.f};
        __builtin_amdgcn_s_setprio(1);
#pragma unroll
        for (int nb = 0; nb < 4; nb++) {
            s16x8 b0 = *(const s16x8*)(&Ks[cur][nb * 16 + ml][quad * 8]);
            s16x8 b1 = *(const s16x8*)(&Ks[cur][nb * 16 + ml][32 + quad * 8]);
            s[nb] = __builtin_amdgcn_mfma_f32_16x16x32_bf16(aq0, b0, s[nb], 0, 0, 0);
            s[nb] = __builtin_amdgcn_mfma_f32_16x16x32_bf16(aq1, b1, s[nb], 0, 0, 0);
        }
        __builtin_amdgcn_s_setprio(0);

        // P = exp(S) (|s|<=0.125, no max needed); masked -> 0; row sums
#pragma unroll
        for (int nb = 0; nb < 4; nb++)
#pragma unroll
            for (int r = 0; r < 4; r++) {
                float pe = __expf(s[nb][r]);
                if (kt == t && (nb * 16 + ml) > (wq * 16 + quad * 4 + r))
                    pe = 0.f;
                ps[r] += pe;
                Ps[wq][quad * 4 + r][nb * 16 + ml] = (short)f2bf(pe);
            }

        s16x8 ap0 = *(const s16x8*)(&Ps[wq][ml][quad * 8]);
        s16x8 ap1 = *(const s16x8*)(&Ps[wq][ml][32 + quad * 8]);
        __builtin_amdgcn_s_setprio(1);
#pragma unroll
        for (int nb = 0; nb < 4; nb++) {
            s16x8 b0 = *(const s16x8*)(&Vs[cur][nb * 16 + ml][quad * 8]);
            s16x8 b1 = *(const s16x8*)(&Vs[cur][nb * 16 + ml][32 + quad * 8]);
            o[nb] = __builtin_amdgcn_mfma_f32_16x16x32_bf16(ap0, b0, o[nb], 0, 0, 0);
            o[nb] = __builtin_amdgcn_mfma_f32_16x16x32_bf16(ap1, b1, o[nb], 0, 0, 0);
        }
        __builtin_amdgcn_s_setprio(0);

        // write tile kt+2 into the other buffer; next iter's barrier covers it
        if (kt + 2 <= t) {
            *(int4*)(&Ks[cur ^ 1][srow][sc])     = kr0;
            *(int4*)(&Ks[cur ^ 1][srow][sc + 8]) = kr1;
            *(int4*)(&Vs[cur ^ 1][srow][sc])     = vr0;
            *(int4*)(&Vs[cur ^ 1][srow][sc + 8]) = vr1;
        }
        cur ^= 1;
    }

    // write partials: o fp32 (coalesced 64/row) and l (one lane per row).
#pragma unroll
    for (int r = 0; r < 4; r++) {
        float l = ps[r];
#pragma unroll
        for (int off = 1; off < 16; off <<= 1)
            l += __shfl_xor(l, off);
        int row = q0 + wq * 16 + quad * 4 + r;
        size_t rb = ((size_t)(half * NH_ + h) * S_ + row) * HD_;
#pragma unroll
        for (int nb = 0; nb < 4; nb++)
            opart[rb + nb * 16 + ml] = o[nb][r];
        if (ml == 0)
            lpart[(size_t)(half * NH_ + h) * S_ + row] = l;
    }
}

// ---------------------------------------------------------------------------
// flash combine: aob[s][h*64+d] = f2bf((o0+o1)/(l0+l1)); 8192 blocks x 256.
// ---------------------------------------------------------------------------
__global__ __launch_bounds__(256) void flash_combine_kernel(
    const float* __restrict__ opart, const float* __restrict__ lpart,
    unsigned short* __restrict__ aob)
{
    int hs = blockIdx.x * 4 + (threadIdx.x >> 6);   // flattened h*S+s
    int d = threadIdx.x & 63;
    int h = hs >> 11;            // /S_
    int s = hs & (S_ - 1);
    size_t i0 = (size_t)hs * HD_ + d;
    size_t i1 = (size_t)(NH_ * S_ + hs) * HD_ + d;
    float l = lpart[hs] + lpart[NH_ * S_ + hs];
    float val = (opart[i0] + opart[i1]) / l;
    aob[((size_t)s * NH_ + h) * HD_ + d] = f2bf(val);
}

// ---------------------------------------------------------------------------
// expert score GEMM, split-K x8: block = (chunk c, k-slice sk).
// ---------------------------------------------------------------------------
__global__ __launch_bounds__(256) void score_gemm_kernel(
    const unsigned short* __restrict__ xfb, const unsigned short* __restrict__ kgath,
    float* __restrict__ msbufp)
{
    __shared__ __align__(16) short As[128][32];
    __shared__ __align__(16) short Bs[128][32];
    int c  = blockIdx.x >> 3;
    int sk = blockIdx.x & 7;
    const unsigned short* A  = xfb   + (size_t)c * 128 * D_ + sk * 128;
    const unsigned short* Bt = kgath + (size_t)c * 128 * D_ + sk * 128;
    int tid = threadIdx.x;
    int wave = tid >> 6, lane = tid & 63;
    int ml = lane & 15, q = lane >> 4;
    int wr = wave >> 1, wc = wave & 1;
    int srow = tid >> 2;
    int scol = (tid & 3) * 8;

    f32x4 acc[4][4];
#pragma unroll
    for (int i = 0; i < 4; i++)
#pragma unroll
        for (int j = 0; j < 4; j++) acc[i][j] = (f32x4){0.f, 0.f, 0.f, 0.f};

    const unsigned short* Ap = A  + (size_t)srow * D_ + scol;
    const unsigned short* Bp = Bt + (size_t)srow * D_ + scol;
    short* ldsA0 = &As[wave * 16][0];
    short* ldsA1 = &As[64 + wave * 16][0];
    short* ldsB0 = &Bs[wave * 16][0];
    short* ldsB1 = &Bs[64 + wave * 16][0];

    for (int k0 = 0; k0 < 128; k0 += 32) {
        __syncthreads();
        GLOAD16(Ap + k0, ldsA0);
        GLOAD16(Ap + (size_t)64 * D_ + k0, ldsA1);
        GLOAD16(Bp + k0, ldsB0);
        GLOAD16(Bp + (size_t)64 * D_ + k0, ldsB1);
        __syncthreads();

        s16x8 af[4], bf[4];
#pragma unroll
        for (int i = 0; i < 4; i++)
            af[i] = *(const s16x8*)(&As[wr * 64 + i * 16 + ml][q * 8]);
#pragma unroll
        for (int j = 0; j < 4; j++)
            bf[j] = *(const s16x8*)(&Bs[wc * 64 + j * 16 + ml][q * 8]);
#pragma unroll
        for (int i = 0; i < 4; i++)
#pragma unroll
            for (int j = 0; j < 4; j++)
                acc[i][j] = __builtin_amdgcn_mfma_f32_16x16x32_bf16(
                    af[i], bf[j], acc[i][j], 0, 0, 0);
    }

    float* out = msbufp + (size_t)blockIdx.x * 128 * 128;
#pragma unroll
    for (int i = 0; i < 4; i++)
#pragma unroll
        for (int j = 0; j < 4; j++) {
            int col = wc * 64 + j * 16 + ml;
#pragma unroll
            for (int r = 0; r < 4; r++) {
                int row = wr * 64 + i * 16 + q * 4 + r;
                out[(size_t)row * 128 + col] = acc[i][j][r];
            }
        }
}

// ---------------------------------------------------------------------------
// MoE with rank-1 experts + fused combine weights; 4 tokens per block.
// ---------------------------------------------------------------------------
__global__ __launch_bounds__(256) void moe_kernel(
    const float* __restrict__ xf, const float* __restrict__ xfi,
    const int* __restrict__ indices, const float* __restrict__ msbufp,
    const float* __restrict__ scores,
    const float* __restrict__ score_probs, const float* __restrict__ head_probs,
    const float* __restrict__ experts, float* __restrict__ out)
{
    int g = blockIdx.x, tid = threadIdx.x;
    int c = g >> 5;
    int t0 = c * NT_ + (g & 31) * 4;
    __shared__ int sidx[ET_];
    __shared__ float sw[4][ET_];
    __shared__ float sact[4][ET_];
    __shared__ float sx[4][D_];
    if (tid < ET_) sidx[tid] = indices[c * ET_ + tid];
#pragma unroll
    for (int tt = 0; tt < 4; tt++)
        ((float4*)sx[tt])[tid] =
            ((const float4*)(xf + (size_t)(t0 + tt) * D_))[tid];
    // ---- phase A: combine weights; thread = (e = tid>>4, hh = tid&15) ----
    {
        int e = tid >> 4, hh = tid & 15;
        int idxe = indices[c * ET_ + e];
        int rr = e >> 2;   // e / DE_
        float sp0 = score_probs[((size_t)rr * E_ + idxe) * H_ + hh];
        float sp1 = score_probs[((size_t)(RE_ + rr) * E_ + idxe) * H_ + hh];
        float hp  = head_probs[((size_t)rr * E_ + idxe) * H_ + hh];
#pragma unroll
        for (int tt = 0; tt < 4; tt++) {
            int t = t0 + tt;
            int trow = t & 127;
            const float* mp = msbufp + ((size_t)(c * 8) * 128 + trow) * 128
                                     + e * 8 + (hh >> 1);
            float ms = 0.f;
#pragma unroll
            for (int sck = 0; sck < 8; sck++)
                ms += mp[(size_t)sck * 128 * 128];
            float scv = scores[(size_t)t * (ET_ * H_) + tid];
            float z = sp0 * ms + sp1 * scv;
            float term = hp / (1.0f + __expf(-z));
#pragma unroll
            for (int off = 1; off < 16; off <<= 1)
                term += __shfl_xor(term, off);
            if (hh == 0) sw[tt][e] = term;
        }
    }
    __syncthreads();   // sx, sw, sidx ready

    // ---- phase B: wave wv computes h0/h1/act for experts 4wv..4wv+3 ----
    int wv = tid >> 6, lane = tid & 63;
#pragma unroll
    for (int ee = 0; ee < 4; ee++) {
        int e = wv * 4 + ee;
        int idx = sidx[e];
        size_t base = (size_t)idx * D_;
        float p0[4] = {0.f, 0.f, 0.f, 0.f};
        float p1[4] = {0.f, 0.f, 0.f, 0.f};
#pragma unroll
        for (int rr = 0; rr < 4; rr++) {
            int dd = rr * 256 + lane * 4;
            float4 w0 = *(const float4*)(experts + base + dd);
            float4 w1 = *(const float4*)(experts + (size_t)E_ * D_ + base + dd);
#pragma unroll
            for (int tt = 0; tt < 4; tt++) {
                float4 xr = *(const float4*)(&sx[tt][dd]);
                p0[tt] += xr.x*w0.x + xr.y*w0.y + xr.z*w0.z + xr.w*w0.w;
                p1[tt] += xr.x*w1.x + xr.y*w1.y + xr.z*w1.z + xr.w*w1.w;
            }
        }
#pragma unroll
        for (int tt = 0; tt < 4; tt++) {
#pragma unroll
            for (int off = 32; off > 0; off >>= 1) {
                p0[tt] += __shfl_xor(p0[tt], off);
                p1[tt] += __shfl_xor(p1[tt], off);
            }
        }
        if (lane == 0) {
#pragma unroll
            for (int tt = 0; tt < 4; tt++)
                sact[tt][e] = p0[tt] / (1.0f + __expf(-p0[tt])) * p1[tt]
                              * sw[tt][e];
        }
    }
    __syncthreads();   // sact ready

    // ---- phase C: accumulate w2, amortized over 4 tokens ----
    float4 a0 = {0,0,0,0}, a1 = {0,0,0,0}, a2 = {0,0,0,0}, a3 = {0,0,0,0};
    const float* w2base = experts + (size_t)2 * E_ * D_;
#pragma unroll
    for (int e = 0; e < ET_; e++) {
        float4 w2 = *(const float4*)(w2base + (size_t)sidx[e] * D_ + tid * 4);
        float c0 = sact[0][e], c1 = sact[1][e], c2 = sact[2][e], c3 = sact[3][e];
        a0.x += c0 * w2.x; a0.y += c0 * w2.y; a0.z += c0 * w2.z; a0.w += c0 * w2.w;
        a1.x += c1 * w2.x; a1.y += c1 * w2.y; a1.z += c1 * w2.z; a1.w += c1 * w2.w;
        a2.x += c2 * w2.x; a2.y += c2 * w2.y; a2.z += c2 * w2.z; a2.w += c2 * w2.w;
        a3.x += c3 * w2.x; a3.y += c3 * w2.y; a3.z += c3 * w2.z; a3.w += c3 * w2.w;
    }
#pragma unroll
    for (int tt = 0; tt < 4; tt++) {
        float4 av = (tt == 0) ? a0 : (tt == 1) ? a1 : (tt == 2) ? a2 : a3;
        size_t o = (size_t)(t0 + tt) * D_ + tid * 4;
        float4 rv = *(const float4*)(xfi + o);
        float4 ov;
        ov.x = av.x + rv.x;
        ov.y = av.y + rv.y;
        ov.z = av.z + rv.z;
        ov.w = av.w + rv.w;
        *(float4*)(out + o) = ov;
    }
}

// ---------------------------------------------------------------------------
extern "C" void kernel_launch(void* const* d_in, const int* in_sizes, int n_in,
                              void* d_out, int out_size, void* d_ws, size_t ws_size,
                              hipStream_t stream)
{
    (void)in_sizes; (void)n_in; (void)out_size; (void)ws_size;
    const float* x_input     = (const float*)d_in[0];
    const int*   indices     = (const int*)d_in[1];
    const float* scores      = (const float*)d_in[2];
    const float* attn_w      = (const float*)d_in[3];
    const float* attn_out_w  = (const float*)d_in[4];
    const float* attn_norm_w = (const float*)d_in[5];
    const float* ffn_norm_w  = (const float*)d_in[6];
    const float* ffn_experts = (const float*)d_in[7];
    const float* keys        = (const float*)d_in[8];
    const float* head_probs  = (const float*)d_in[9];
    const float* score_probs = (const float*)d_in[10];
    float* out = (float*)d_out;

    float* ws = (float*)d_ws;
    const size_t MF = 1024 * 1024;
    // Region map (floats), peak ~18.1M floats = 72 MB:
    // qh    [0,1M)    bf16     (gemm_qkv -> flash)
    // khb   [1M,2M)   bf16
    // tmpT  [2M,3M)   bf16     (preprocess -> transpose_keys)
    // vhT   [3M,4M)   bf16     (gemm_qkv -> flash, written transposed)
    // xfi   [4M,6M)   f32      (gemm2 -> rmsnorm_dual, moe)
    // xnb   [6M,7M)   bf16     (preprocess -> gemm_qkv); reused: aob (combine->gemm2)
    // woutT [7M,7.5M) bf16     (preprocess -> gemm2)
    // wqkvT [8M,9.5M) bf16     (preprocess -> gemm_qkv); reused: xf [8M,10M) f32
    // kgath [10M,11M) bf16     (transpose_keys -> score_gemm)
    // xfb   [11M,12M) bf16     (rmsnorm_dual -> score_gemm)
    // msbufp[12M,14M) f32      (score_gemm -> moe)
    // opart [14M,18M) f32      (flash -> combine)   2 x 16 x 2048 x 64
    // lpart [18M,+64K) f32     (flash -> combine)
    unsigned short* qh    = (unsigned short*)ws;
    unsigned short* khb   = (unsigned short*)(ws + 1 * MF);
    unsigned short* tmpT  = (unsigned short*)(ws + 2 * MF);
    unsigned short* vhT   = (unsigned short*)(ws + 3 * MF);
    float* xfi            = ws + 4 * MF;
    unsigned short* xnb   = (unsigned short*)(ws + 6 * MF);
    unsigned short* aob   = (unsigned short*)(ws + 6 * MF);
    unsigned short* woutT = (unsigned short*)(ws + 7 * MF);
    unsigned short* wqkvT = (unsigned short*)(ws + 8 * MF);
    float* xf             = ws + 8 * MF;
    unsigned short* kgath = (unsigned short*)(ws + 10 * MF);
    unsigned short* xfb   = (unsigned short*)(ws + 11 * MF);
    float* msbufp         = ws + 12 * MF;
    float* opart          = ws + 14 * MF;
    float* lpart          = ws + 18 * MF;

    // 1) mega-preprocess: rmsnorm + weight transposes + keys compact
    preprocess_kernel<<<14336, 256, 0, stream>>>(
        x_input, attn_norm_w, xnb, attn_w, wqkvT, attn_out_w, woutT,
        keys, indices, tmpT);

    // 1.5) keys transpose: tmpT [kh][d][pair] -> kgath Bt layout
    {
        dim3 g(256 / 32, D_ / 32, KH_);
        transpose_keys_kernel<<<g, 256, 0, stream>>>(tmpT, kgath);
    }

    // 2) fused qkv GEMM + l2norm + rope + head split; V written transposed
    {
        dim3 g(3 * D_ / 128, T_ / 128);
        mfma_gemm_qkv_kernel<<<g, 256, 0, stream>>>(xnb, wqkvT, qh, khb, vhT);
    }

    // 3) MFMA flash attention, split-K x2 -> opart/lpart partials
    flash_attn_mfma_kernel<<<2 * (S_ / 64) * NH_, 256, 0, stream>>>(
        qh, khb, vhT, opart, lpart);

    // 3.5) combine partials -> aob bf16
    flash_combine_kernel<<<NH_ * S_ / 4, 256, 0, stream>>>(opart, lpart, aob);

    // 4) xfi = aob @ attn_out_w + x_input   (MFMA + residual, 128^2 tiles)
    {
        dim3 g(D_ / 128, T_ / 128);
        mfma_gemm_kernel<1><<<g, 256, 0, stream>>>(aob, woutT, x_input, xfi,
                                                   T_, D_, D_);
    }

    // 5) rmsnorm dual: xf fp32 + xfb bf16
    rmsnorm_dual_kernel<<<T_, 256, 0, stream>>>(xfi, ffn_norm_w, xf, xfb);

    // 6) expert score GEMM, split-K x8 -> msbufp partials
    score_gemm_kernel<<<BC_ * 8, 256, 0, stream>>>(xfb, kgath, msbufp);

    // 7) MoE (4 tokens/block, combine weights fused) + final residual
    moe_kernel<<<T_ / 4, 256, 0, stream>>>(xf, xfi, indices, msbufp, scores,
                                           score_probs, head_probs,
                                           ffn_experts, out);
}

// Round 10
// 370.244 us; speedup vs baseline: 1.0248x; 1.0248x over previous
//
#include <hip/hip_runtime.h>
#include <hip/hip_bf16.h>
#include <math.h>

// Problem constants
#define D_   1024
#define HD_  64
#define NH_  16
#define H_   16
#define KH_  8
#define NT_  128      // tokens per chunk (N)
#define E_   4096
#define RE_  4
#define DE_  4
#define ET_  16
#define S_   2048
#define T_   2048
#define BC_  16
#define EPS_ 1e-5f

typedef short s16x8 __attribute__((ext_vector_type(8)));
typedef float f32x4 __attribute__((ext_vector_type(4)));

__device__ __forceinline__ unsigned short f2bf(float f) {
    union { float f; unsigned int u; } v; v.f = f;
    unsigned int r = (v.u + 0x7fffu + ((v.u >> 16) & 1u)) >> 16;  // RNE
    return (unsigned short)r;
}

// async global->LDS, 16B per lane; LDS dest is wave-uniform base + lane*16.
#define GLOAD16(gp, lp) __builtin_amdgcn_global_load_lds(                      \
    (__attribute__((address_space(1))) void*)(gp),                             \
    (__attribute__((address_space(3))) void*)(lp), 16, 0, 0)

// ---------------------------------------------------------------------------
// Mega-preprocess (input-only dependencies), one launch:
//   [0,2048):     rmsnorm(x_input) -> xnb bf16
//   [2048,5120):  convt attn_w (1024x3072) -> wqkvT [3072][1024] bf16
//   [5120,6144):  convt attn_out_w (1024x1024) -> woutT [1024][1024] bf16
//   [6144,14336): keys compact: block (kh,d) reads row keys[kh][d][:]
//                 COALESCED (16KB), LDS-stages, picks the 256 indexed cols ->
//                 tmpT[kh][d][pair] bf16.
// ---------------------------------------------------------------------------
__global__ __launch_bounds__(256) void preprocess_kernel(
    const float* __restrict__ x, const float* __restrict__ attn_norm_w,
    unsigned short* __restrict__ xnb,
    const float* __restrict__ attn_w, unsigned short* __restrict__ wqkvT,
    const float* __restrict__ attn_out_w, unsigned short* __restrict__ woutT,
    const float* __restrict__ keys, const int* __restrict__ indices,
    unsigned short* __restrict__ tmpT)
{
    __shared__ float tile[32][33];
    __shared__ float sred[4];
    __shared__ float rowbuf[E_];
    int bid = blockIdx.x, tid = threadIdx.x;

    if (bid < 2048) {
        // ---- rmsnorm -> bf16 ----
        int row = bid;
        float4 v = ((const float4*)(x + (size_t)row * D_))[tid];
        float ss = v.x*v.x + v.y*v.y + v.z*v.z + v.w*v.w;
#pragma unroll
        for (int off = 32; off > 0; off >>= 1) ss += __shfl_xor(ss, off);
        if ((tid & 63) == 0) sred[tid >> 6] = ss;
        __syncthreads();
        float tot = sred[0] + sred[1] + sred[2] + sred[3];
        float scale = rsqrtf(tot * (1.0f / D_) + EPS_);
        float4 wv = ((const float4*)attn_norm_w)[tid];
        ushort4 o;
        o.x = f2bf(v.x * scale * wv.x);
        o.y = f2bf(v.y * scale * wv.y);
        o.z = f2bf(v.z * scale * wv.z);
        o.w = f2bf(v.w * scale * wv.w);
        *(ushort4*)(xnb + (size_t)row * D_ + tid * 4) = o;
    } else if (bid < 6144) {
        // ---- convert + transpose weight ----
        const float* src; unsigned short* dst; int R, Ncols, bx, by;
        if (bid < 5120) {
            int cid = bid - 2048;
            src = attn_w; dst = wqkvT; R = D_; Ncols = 3 * D_;
            bx = (cid % 96) * 32; by = (cid / 96) * 32;
        } else {
            int cid = bid - 5120;
            src = attn_out_w; dst = woutT; R = D_; Ncols = D_;
            bx = (cid & 31) * 32; by = (cid >> 5) * 32;
        }
        int tx = tid & 31, ty = tid >> 5;
#pragma unroll
        for (int rr = 0; rr < 32; rr += 8)
            tile[ty + rr][tx] = src[(size_t)(by + ty + rr) * Ncols + bx + tx];
        __syncthreads();
#pragma unroll
        for (int rr = 0; rr < 32; rr += 8)
            dst[(size_t)(bx + ty + rr) * R + by + tx] = f2bf(tile[tx][ty + rr]);
    } else {
        // ---- keys compact: coalesced row read + LDS column pick ----
        int id = bid - 6144;          // 0..8191
        int kh = id >> 10;            // /D_
        int d  = id & (D_ - 1);
        const float* rowp = keys + ((size_t)kh * D_ + d) * E_;
#pragma unroll
        for (int pass = 0; pass < 4; pass++)
            ((float4*)rowbuf)[tid + pass * 256] =
                ((const float4*)rowp)[tid + pass * 256];
        __syncthreads();
        int idx = indices[tid];       // pair = tid (256 pairs)
        tmpT[((size_t)kh * D_ + d) * 256 + tid] = f2bf(rowbuf[idx]);
    }
}

// rmsnorm dual: fp32 out + bf16 out
__global__ __launch_bounds__(256) void rmsnorm_dual_kernel(
    const float* __restrict__ x, const float* __restrict__ w,
    float* __restrict__ out, unsigned short* __restrict__ outb)
{
    int row = blockIdx.x, tid = threadIdx.x;
    __shared__ float sred[4];
    float4 v = ((const float4*)(x + (size_t)row * D_))[tid];
    float ss = v.x*v.x + v.y*v.y + v.z*v.z + v.w*v.w;
#pragma unroll
    for (int off = 32; off > 0; off >>= 1) ss += __shfl_xor(ss, off);
    if ((tid & 63) == 0) sred[tid >> 6] = ss;
    __syncthreads();
    float tot = sred[0] + sred[1] + sred[2] + sred[3];
    float scale = rsqrtf(tot * (1.0f / D_) + EPS_);
    float4 wv = ((const float4*)w)[tid];
    float4 o;
    o.x = v.x * scale * wv.x;
    o.y = v.y * scale * wv.y;
    o.z = v.z * scale * wv.z;
    o.w = v.w * scale * wv.w;
    ((float4*)(out + (size_t)row * D_))[tid] = o;
    ushort4 ob;
    ob.x = f2bf(o.x); ob.y = f2bf(o.y); ob.z = f2bf(o.z); ob.w = f2bf(o.w);
    *(ushort4*)(outb + (size_t)row * D_ + tid * 4) = ob;
}

// ---------------------------------------------------------------------------
// MFMA GEMM: C[M,N] fp32 = A[M,K] bf16 @ Bt[N,K] bf16 (+ res fp32)
// ---------------------------------------------------------------------------
template <int WITH_RES>
__global__ __launch_bounds__(256) void mfma_gemm_kernel(
    const unsigned short* __restrict__ A, const unsigned short* __restrict__ Bt,
    const float* __restrict__ res, float* __restrict__ C,
    int M, int N, int K)
{
    __shared__ __align__(16) short As[128][32];
    __shared__ __align__(16) short Bs[128][32];
    int tid = threadIdx.x;
    int wave = tid >> 6, lane = tid & 63;
    int ml = lane & 15, q = lane >> 4;
    int wr = wave >> 1, wc = wave & 1;
    int bm = blockIdx.y * 128, bn = blockIdx.x * 128;
    int srow = tid >> 2;           // 0..63
    int scol = (tid & 3) * 8;      // shorts

    f32x4 acc[4][4];
#pragma unroll
    for (int i = 0; i < 4; i++)
#pragma unroll
        for (int j = 0; j < 4; j++) acc[i][j] = (f32x4){0.f, 0.f, 0.f, 0.f};

    const unsigned short* Ap = A  + (size_t)(bm + srow) * K + scol;
    const unsigned short* Bp = Bt + (size_t)(bn + srow) * K + scol;
    short* ldsA0 = &As[wave * 16][0];
    short* ldsA1 = &As[64 + wave * 16][0];
    short* ldsB0 = &Bs[wave * 16][0];
    short* ldsB1 = &Bs[64 + wave * 16][0];

    for (int k0 = 0; k0 < K; k0 += 32) {
        __syncthreads();
        GLOAD16(Ap + k0, ldsA0);
        GLOAD16(Ap + (size_t)64 * K + k0, ldsA1);
        GLOAD16(Bp + k0, ldsB0);
        GLOAD16(Bp + (size_t)64 * K + k0, ldsB1);
        __syncthreads();

        s16x8 af[4], bf[4];
#pragma unroll
        for (int i = 0; i < 4; i++)
            af[i] = *(const s16x8*)(&As[wr * 64 + i * 16 + ml][q * 8]);
#pragma unroll
        for (int j = 0; j < 4; j++)
            bf[j] = *(const s16x8*)(&Bs[wc * 64 + j * 16 + ml][q * 8]);
#pragma unroll
        for (int i = 0; i < 4; i++)
#pragma unroll
            for (int j = 0; j < 4; j++)
                acc[i][j] = __builtin_amdgcn_mfma_f32_16x16x32_bf16(
                    af[i], bf[j], acc[i][j], 0, 0, 0);
    }

#pragma unroll
    for (int i = 0; i < 4; i++) {
#pragma unroll
        for (int j = 0; j < 4; j++) {
            int col = bn + wc * 64 + j * 16 + ml;
#pragma unroll
            for (int r = 0; r < 4; r++) {
                int row = bm + wr * 64 + i * 16 + q * 4 + r;
                float v = acc[i][j][r];
                if (WITH_RES) v += res[(size_t)row * N + col];
                C[(size_t)row * N + col] = v;
            }
        }
    }
}

// ---------------------------------------------------------------------------
// Fused QKV GEMM + keys transpose (independent work, one launch):
//   bid <  384:  qkv GEMM block (gx = bid%24 in [0,24) col-tile, gy = bid/24
//                row-tile). Epilogue l2norm + rope + split; V written
//                directly transposed (vhT[h][d][s]).
//   bid >= 384:  keys transpose tile: tmpT [kh][d][pair] ->
//                kgath[(pair>>4)*128+(pair&15)*8+kh][d].
// ---------------------------------------------------------------------------
__global__ __launch_bounds__(256) void mfma_gemm_qkv_kernel(
    const unsigned short* __restrict__ A, const unsigned short* __restrict__ Bt,
    unsigned short* __restrict__ qh, unsigned short* __restrict__ khb,
    unsigned short* __restrict__ vhT,
    const unsigned short* __restrict__ tmpT, unsigned short* __restrict__ kgath)
{
    const int K = D_;
    __shared__ __align__(16) short As[128][32];
    __shared__ __align__(16) short Bs[128][32];
    __shared__ unsigned short ttile[32][34];
    int bid = blockIdx.x;
    int tid = threadIdx.x;

    if (bid >= 384) {
        // ---- keys transpose tile ----
        int id = bid - 384;           // 0..2047
        int p0 = (id & 7) * 32;       // pair tile (8)
        int d0 = ((id >> 3) & 31) * 32;  // d tile (32)
        int kh = id >> 8;             // (8)
        int tx = tid & 31, ty = tid >> 5;
#pragma unroll
        for (int rr = 0; rr < 32; rr += 8)
            ttile[ty + rr][tx] =
                tmpT[((size_t)kh * D_ + d0 + ty + rr) * 256 + p0 + tx];
        __syncthreads();
#pragma unroll
        for (int rr = 0; rr < 32; rr += 8) {
            int p = p0 + ty + rr;
            int n = (p >> 4) * 128 + (p & 15) * 8 + kh;
            kgath[(size_t)n * D_ + d0 + tx] = ttile[tx][ty + rr];
        }
        return;
    }

    int gx = bid % 24, gy = bid / 24;
    int wave = tid >> 6, lane = tid & 63;
    int ml = lane & 15, q = lane >> 4;
    int wr = wave >> 1, wc = wave & 1;
    int bm = gy * 128, bn = gx * 128;
    int srow = tid >> 2;
    int scol = (tid & 3) * 8;

    f32x4 acc[4][4];
#pragma unroll
    for (int i = 0; i < 4; i++)
#pragma unroll
        for (int j = 0; j < 4; j++) acc[i][j] = (f32x4){0.f, 0.f, 0.f, 0.f};

    const unsigned short* Ap = A  + (size_t)(bm + srow) * K + scol;
    const unsigned short* Bp = Bt + (size_t)(bn + srow) * K + scol;
    short* ldsA0 = &As[wave * 16][0];
    short* ldsA1 = &As[64 + wave * 16][0];
    short* ldsB0 = &Bs[wave * 16][0];
    short* ldsB1 = &Bs[64 + wave * 16][0];

    for (int k0 = 0; k0 < K; k0 += 32) {
        __syncthreads();
        GLOAD16(Ap + k0, ldsA0);
        GLOAD16(Ap + (size_t)64 * K + k0, ldsA1);
        GLOAD16(Bp + k0, ldsB0);
        GLOAD16(Bp + (size_t)64 * K + k0, ldsB1);
        __syncthreads();

        s16x8 af[4], bf[4];
#pragma unroll
        for (int i = 0; i < 4; i++)
            af[i] = *(const s16x8*)(&As[wr * 64 + i * 16 + ml][q * 8]);
#pragma unroll
        for (int j = 0; j < 4; j++)
            bf[j] = *(const s16x8*)(&Bs[wc * 64 + j * 16 + ml][q * 8]);
#pragma unroll
        for (int i = 0; i < 4; i++)
#pragma unroll
            for (int j = 0; j < 4; j++)
                acc[i][j] = __builtin_amdgcn_mfma_f32_16x16x32_bf16(
                    af[i], bf[j], acc[i][j], 0, 0, 0);
    }

    // ---- epilogue: l2norm + rope + bf16 split write ----
    int sel = gx >> 3;                  // 0:q 1:k 2:v
    int h = ((gx & 7) << 1) + wc;       // head for this wave
    float qscale = (sel == 0) ? 0.125f : 1.0f;  // fold 1/sqrt(64) into q
    float if0 = exp2f((float)ml * (-13.287712379549449f / 32.0f));
    float if1 = exp2f((float)(16 + ml) * (-13.287712379549449f / 32.0f));

#pragma unroll
    for (int i = 0; i < 4; i++) {
#pragma unroll
        for (int r = 0; r < 4; r++) {
            int row = bm + wr * 64 + i * 16 + q * 4 + r;
            float v0 = acc[i][0][r], v1 = acc[i][1][r];
            float v2 = acc[i][2][r], v3 = acc[i][3][r];
            if (sel < 2) {
                float ss = v0*v0 + v1*v1 + v2*v2 + v3*v3;
#pragma unroll
                for (int off = 1; off < 16; off <<= 1)
                    ss += __shfl_xor(ss, off);
                float inv = qscale / fmaxf(sqrtf(ss), EPS_);
                v0 *= inv; v1 *= inv; v2 *= inv; v3 *= inv;
                float sn0, cs0, sn1, cs1;
                sincosf((float)row * if0, &sn0, &cs0);
                sincosf((float)row * if1, &sn1, &cs1);
                float o0 = v0 * cs0 + v2 * sn0;
                float o2 = v2 * cs0 - v0 * sn0;
                float o1 = v1 * cs1 + v3 * sn1;
                float o3 = v3 * cs1 - v1 * sn1;
                v0 = o0; v1 = o1; v2 = o2; v3 = o3;
                unsigned short* dst = (sel == 0) ? qh : khb;
                size_t base = ((size_t)h * S_ + row) * HD_;
                dst[base +      ml] = f2bf(v0);
                dst[base + 16 + ml] = f2bf(v1);
                dst[base + 32 + ml] = f2bf(v2);
                dst[base + 48 + ml] = f2bf(v3);
            } else {
                // V: write transposed vhT[h][d][row], d = k*16 + ml
                size_t base = ((size_t)h * HD_ + ml) * S_ + row;
                vhT[base            ] = f2bf(v0);
                vhT[base + 16 * S_  ] = f2bf(v1);
                vhT[base + 32 * S_  ] = f2bf(v2);
                vhT[base + 48 * S_  ] = f2bf(v3);
            }
        }
    }
}

// ---------------------------------------------------------------------------
// MFMA bf16 flash attention, double-buffered LDS, ONE barrier per k-iter.
// XCD-aware mapping: bid = (xcd = bid&7, j = bid>>3); head h = 2*xcd + (j&1)
// so each XCD owns exactly 2 heads -> K + V^T (1 MB) stays L2-resident.
// Heavy/light pairing preserved: j<32 gives t=0..15, j>=32 gives t=31..16.
// Bounded-score softmax (|s|<=0.125 by Cauchy-Schwarz, no online max).
// [R9's split-K x2 variant regressed +7us: partial round-trip + duplicated
//  fixed overheads exceeded the halved serial chain. Reverted to this form.]
// ---------------------------------------------------------------------------
#define FS 72   // shorts per LDS row (pad: 144B rows -> 2-way banks, free)
__global__ __launch_bounds__(256) void flash_attn_mfma_kernel(
    const unsigned short* __restrict__ qh, const unsigned short* __restrict__ khb,
    const unsigned short* __restrict__ vhT, unsigned short* __restrict__ aob)
{
    __shared__ __align__(16) short Ks[2][64][FS];
    __shared__ __align__(16) short Vs[2][64][FS];   // [buf][d][token]
    __shared__ __align__(16) short Ps[4][16][FS];   // per-wave scratch
    int b = blockIdx.x;
    int xcd = b & 7, j = b >> 3;
    int h = 2 * xcd + (j & 1);
    int pp = (j >> 1) & 15;
    int t = (j >> 5) ? (31 - pp) : pp;
    int tid = threadIdx.x;
    int wq = tid >> 6;
    int lane = tid & 63;
    int ml = lane & 15, quad = lane >> 4;
    int srow = tid >> 2;          // 0..63
    int sc = (tid & 3) * 16;      // 0,16,32,48 (shorts)
    const unsigned short* Qb = qh  + (size_t)h * S_ * HD_;
    const unsigned short* Kb = khb + (size_t)h * S_ * HD_;
    const unsigned short* Vt = vhT + (size_t)h * HD_ * S_;

    int q0 = t * 64;
    int qrow = q0 + wq * 16 + ml;
    s16x8 aq0 = *(const s16x8*)(Qb + (size_t)qrow * HD_ + quad * 8);
    s16x8 aq1 = *(const s16x8*)(Qb + (size_t)qrow * HD_ + 32 + quad * 8);

    float ps[4];                  // per-lane partial row sums
    f32x4 o[4];
#pragma unroll
    for (int r = 0; r < 4; r++) ps[r] = 0.f;
#pragma unroll
    for (int nb = 0; nb < 4; nb++) o[nb] = (f32x4){0.f, 0.f, 0.f, 0.f};

    int4 kr0, kr1, vr0, vr1;      // staging registers
    // prologue: tile 0 -> buf 0 (visibility covered by iter-0 top barrier)
    {
        const unsigned short* kp = Kb + (size_t)srow * HD_ + sc;
        kr0 = *(const int4*)kp; kr1 = *(const int4*)(kp + 8);
        const unsigned short* vp = Vt + (size_t)srow * S_ + sc;
        vr0 = *(const int4*)vp; vr1 = *(const int4*)(vp + 8);
        *(int4*)(&Ks[0][srow][sc]) = kr0; *(int4*)(&Ks[0][srow][sc + 8]) = kr1;
        *(int4*)(&Vs[0][srow][sc]) = vr0; *(int4*)(&Vs[0][srow][sc + 8]) = vr1;
    }

    for (int kt = 0; kt <= t; kt++) {
        int k0 = kt * 64;
        int cur = kt & 1;
        // issue next tile's global loads early (latency hides under compute)
        if (kt < t) {
            const unsigned short* kp = Kb + (size_t)(k0 + 64 + srow) * HD_ + sc;
            kr0 = *(const int4*)kp; kr1 = *(const int4*)(kp + 8);
            const unsigned short* vp = Vt + (size_t)srow * S_ + k0 + 64 + sc;
            vr0 = *(const int4*)vp; vr1 = *(const int4*)(vp + 8);
        }
        __syncthreads();           // single barrier per iteration

        f32x4 s[4];
#pragma unroll
        for (int nb = 0; nb < 4; nb++) s[nb] = (f32x4){0.f, 0.f, 0.f, 0.f};
        __builtin_amdgcn_s_setprio(1);
#pragma unroll
        for (int nb = 0; nb < 4; nb++) {
            s16x8 b0 = *(const s16x8*)(&Ks[cur][nb * 16 + ml][quad * 8]);
            s16x8 b1 = *(const s16x8*)(&Ks[cur][nb * 16 + ml][32 + quad * 8]);
            s[nb] = __builtin_amdgcn_mfma_f32_16x16x32_bf16(aq0, b0, s[nb], 0, 0, 0);
            s[nb] = __builtin_amdgcn_mfma_f32_16x16x32_bf16(aq1, b1, s[nb], 0, 0, 0);
        }
        __builtin_amdgcn_s_setprio(0);

        // P = exp(S) (bounded, no max needed); masked -> 0; per-lane row sums
#pragma unroll
        for (int nb = 0; nb < 4; nb++)
#pragma unroll
            for (int r = 0; r < 4; r++) {
                float pe = __expf(s[nb][r]);
                if (kt == t && (nb * 16 + ml) > (wq * 16 + quad * 4 + r))
                    pe = 0.f;
                ps[r] += pe;
                Ps[wq][quad * 4 + r][nb * 16 + ml] = (short)f2bf(pe);
            }

        s16x8 ap0 = *(const s16x8*)(&Ps[wq][ml][quad * 8]);
        s16x8 ap1 = *(const s16x8*)(&Ps[wq][ml][32 + quad * 8]);
        __builtin_amdgcn_s_setprio(1);
#pragma unroll
        for (int nb = 0; nb < 4; nb++) {
            s16x8 b0 = *(const s16x8*)(&Vs[cur][nb * 16 + ml][quad * 8]);
            s16x8 b1 = *(const s16x8*)(&Vs[cur][nb * 16 + ml][32 + quad * 8]);
            o[nb] = __builtin_amdgcn_mfma_f32_16x16x32_bf16(ap0, b0, o[nb], 0, 0, 0);
            o[nb] = __builtin_amdgcn_mfma_f32_16x16x32_bf16(ap1, b1, o[nb], 0, 0, 0);
        }
        __builtin_amdgcn_s_setprio(0);

        // write next tile into the other buffer; next iter's barrier covers it
        if (kt < t) {
            *(int4*)(&Ks[cur ^ 1][srow][sc])     = kr0;
            *(int4*)(&Ks[cur ^ 1][srow][sc + 8]) = kr1;
            *(int4*)(&Vs[cur ^ 1][srow][sc])     = vr0;
            *(int4*)(&Vs[cur ^ 1][srow][sc + 8]) = vr1;
        }
    }

    // final: reduce row sums over the 16 ml lanes (same quad), normalize.
#pragma unroll
    for (int r = 0; r < 4; r++) {
        float l = ps[r];
#pragma unroll
        for (int off = 1; off < 16; off <<= 1)
            l += __shfl_xor(l, off);
        float inv = 1.0f / l;
        int row = q0 + wq * 16 + quad * 4 + r;
#pragma unroll
        for (int nb = 0; nb < 4; nb++)
            aob[(size_t)row * D_ + h * HD_ + nb * 16 + ml] =
                f2bf(o[nb][r] * inv);
    }
}

// ---------------------------------------------------------------------------
// expert score GEMM, split-K x8: block = (chunk c, k-slice sk).
// ---------------------------------------------------------------------------
__global__ __launch_bounds__(256) void score_gemm_kernel(
    const unsigned short* __restrict__ xfb, const unsigned short* __restrict__ kgath,
    float* __restrict__ msbufp)
{
    __shared__ __align__(16) short As[128][32];
    __shared__ __align__(16) short Bs[128][32];
    int c  = blockIdx.x >> 3;
    int sk = blockIdx.x & 7;
    const unsigned short* A  = xfb   + (size_t)c * 128 * D_ + sk * 128;
    const unsigned short* Bt = kgath + (size_t)c * 128 * D_ + sk * 128;
    int tid = threadIdx.x;
    int wave = tid >> 6, lane = tid & 63;
    int ml = lane & 15, q = lane >> 4;
    int wr = wave >> 1, wc = wave & 1;
    int srow = tid >> 2;
    int scol = (tid & 3) * 8;

    f32x4 acc[4][4];
#pragma unroll
    for (int i = 0; i < 4; i++)
#pragma unroll
        for (int j = 0; j < 4; j++) acc[i][j] = (f32x4){0.f, 0.f, 0.f, 0.f};

    const unsigned short* Ap = A  + (size_t)srow * D_ + scol;
    const unsigned short* Bp = Bt + (size_t)srow * D_ + scol;
    short* ldsA0 = &As[wave * 16][0];
    short* ldsA1 = &As[64 + wave * 16][0];
    short* ldsB0 = &Bs[wave * 16][0];
    short* ldsB1 = &Bs[64 + wave * 16][0];

    for (int k0 = 0; k0 < 128; k0 += 32) {
        __syncthreads();
        GLOAD16(Ap + k0, ldsA0);
        GLOAD16(Ap + (size_t)64 * D_ + k0, ldsA1);
        GLOAD16(Bp + k0, ldsB0);
        GLOAD16(Bp + (size_t)64 * D_ + k0, ldsB1);
        __syncthreads();

        s16x8 af[4], bf[4];
#pragma unroll
        for (int i = 0; i < 4; i++)
            af[i] = *(const s16x8*)(&As[wr * 64 + i * 16 + ml][q * 8]);
#pragma unroll
        for (int j = 0; j < 4; j++)
            bf[j] = *(const s16x8*)(&Bs[wc * 64 + j * 16 + ml][q * 8]);
#pragma unroll
        for (int i = 0; i < 4; i++)
#pragma unroll
            for (int j = 0; j < 4; j++)
                acc[i][j] = __builtin_amdgcn_mfma_f32_16x16x32_bf16(
                    af[i], bf[j], acc[i][j], 0, 0, 0);
    }

    float* out = msbufp + (size_t)blockIdx.x * 128 * 128;
#pragma unroll
    for (int i = 0; i < 4; i++)
#pragma unroll
        for (int j = 0; j < 4; j++) {
            int col = wc * 64 + j * 16 + ml;
#pragma unroll
            for (int r = 0; r < 4; r++) {
                int row = wr * 64 + i * 16 + q * 4 + r;
                out[(size_t)row * 128 + col] = acc[i][j][r];
            }
        }
}

// ---------------------------------------------------------------------------
// MoE with rank-1 experts + fused combine weights; 4 tokens per block.
// ---------------------------------------------------------------------------
__global__ __launch_bounds__(256) void moe_kernel(
    const float* __restrict__ xf, const float* __restrict__ xfi,
    const int* __restrict__ indices, const float* __restrict__ msbufp,
    const float* __restrict__ scores,
    const float* __restrict__ score_probs, const float* __restrict__ head_probs,
    const float* __restrict__ experts, float* __restrict__ out)
{
    int g = blockIdx.x, tid = threadIdx.x;
    int c = g >> 5;
    int t0 = c * NT_ + (g & 31) * 4;
    __shared__ int sidx[ET_];
    __shared__ float sw[4][ET_];
    __shared__ float sact[4][ET_];
    __shared__ float sx[4][D_];
    if (tid < ET_) sidx[tid] = indices[c * ET_ + tid];
#pragma unroll
    for (int tt = 0; tt < 4; tt++)
        ((float4*)sx[tt])[tid] =
            ((const float4*)(xf + (size_t)(t0 + tt) * D_))[tid];
    // ---- phase A: combine weights; thread = (e = tid>>4, hh = tid&15) ----
    {
        int e = tid >> 4, hh = tid & 15;
        int idxe = indices[c * ET_ + e];
        int rr = e >> 2;   // e / DE_
        float sp0 = score_probs[((size_t)rr * E_ + idxe) * H_ + hh];
        float sp1 = score_probs[((size_t)(RE_ + rr) * E_ + idxe) * H_ + hh];
        float hp  = head_probs[((size_t)rr * E_ + idxe) * H_ + hh];
#pragma unroll
        for (int tt = 0; tt < 4; tt++) {
            int t = t0 + tt;
            int trow = t & 127;
            const float* mp = msbufp + ((size_t)(c * 8) * 128 + trow) * 128
                                     + e * 8 + (hh >> 1);
            float ms = 0.f;
#pragma unroll
            for (int sck = 0; sck < 8; sck++)
                ms += mp[(size_t)sck * 128 * 128];
            float scv = scores[(size_t)t * (ET_ * H_) + tid];
            float z = sp0 * ms + sp1 * scv;
            float term = hp / (1.0f + __expf(-z));
#pragma unroll
            for (int off = 1; off < 16; off <<= 1)
                term += __shfl_xor(term, off);
            if (hh == 0) sw[tt][e] = term;
        }
    }
    __syncthreads();   // sx, sw, sidx ready

    // ---- phase B: wave wv computes h0/h1/act for experts 4wv..4wv+3 ----
    int wv = tid >> 6, lane = tid & 63;
#pragma unroll
    for (int ee = 0; ee < 4; ee++) {
        int e = wv * 4 + ee;
        int idx = sidx[e];
        size_t base = (size_t)idx * D_;
        float p0[4] = {0.f, 0.f, 0.f, 0.f};
        float p1[4] = {0.f, 0.f, 0.f, 0.f};
#pragma unroll
        for (int rr = 0; rr < 4; rr++) {
            int dd = rr * 256 + lane * 4;
            float4 w0 = *(const float4*)(experts + base + dd);
            float4 w1 = *(const float4*)(experts + (size_t)E_ * D_ + base + dd);
#pragma unroll
            for (int tt = 0; tt < 4; tt++) {
                float4 xr = *(const float4*)(&sx[tt][dd]);
                p0[tt] += xr.x*w0.x + xr.y*w0.y + xr.z*w0.z + xr.w*w0.w;
                p1[tt] += xr.x*w1.x + xr.y*w1.y + xr.z*w1.z + xr.w*w1.w;
            }
        }
#pragma unroll
        for (int tt = 0; tt < 4; tt++) {
#pragma unroll
            for (int off = 32; off > 0; off >>= 1) {
                p0[tt] += __shfl_xor(p0[tt], off);
                p1[tt] += __shfl_xor(p1[tt], off);
            }
        }
        if (lane == 0) {
#pragma unroll
            for (int tt = 0; tt < 4; tt++)
                sact[tt][e] = p0[tt] / (1.0f + __expf(-p0[tt])) * p1[tt]
                              * sw[tt][e];
        }
    }
    __syncthreads();   // sact ready

    // ---- phase C: accumulate w2, amortized over 4 tokens ----
    float4 a0 = {0,0,0,0}, a1 = {0,0,0,0}, a2 = {0,0,0,0}, a3 = {0,0,0,0};
    const float* w2base = experts + (size_t)2 * E_ * D_;
#pragma unroll
    for (int e = 0; e < ET_; e++) {
        float4 w2 = *(const float4*)(w2base + (size_t)sidx[e] * D_ + tid * 4);
        float c0 = sact[0][e], c1 = sact[1][e], c2 = sact[2][e], c3 = sact[3][e];
        a0.x += c0 * w2.x; a0.y += c0 * w2.y; a0.z += c0 * w2.z; a0.w += c0 * w2.w;
        a1.x += c1 * w2.x; a1.y += c1 * w2.y; a1.z += c1 * w2.z; a1.w += c1 * w2.w;
        a2.x += c2 * w2.x; a2.y += c2 * w2.y; a2.z += c2 * w2.z; a2.w += c2 * w2.w;
        a3.x += c3 * w2.x; a3.y += c3 * w2.y; a3.z += c3 * w2.z; a3.w += c3 * w2.w;
    }
#pragma unroll
    for (int tt = 0; tt < 4; tt++) {
        float4 av = (tt == 0) ? a0 : (tt == 1) ? a1 : (tt == 2) ? a2 : a3;
        size_t o = (size_t)(t0 + tt) * D_ + tid * 4;
        float4 rv = *(const float4*)(xfi + o);
        float4 ov;
        ov.x = av.x + rv.x;
        ov.y = av.y + rv.y;
        ov.z = av.z + rv.z;
        ov.w = av.w + rv.w;
        *(float4*)(out + o) = ov;
    }
}

// ---------------------------------------------------------------------------
extern "C" void kernel_launch(void* const* d_in, const int* in_sizes, int n_in,
                              void* d_out, int out_size, void* d_ws, size_t ws_size,
                              hipStream_t stream)
{
    (void)in_sizes; (void)n_in; (void)out_size; (void)ws_size;
    const float* x_input     = (const float*)d_in[0];
    const int*   indices     = (const int*)d_in[1];
    const float* scores      = (const float*)d_in[2];
    const float* attn_w      = (const float*)d_in[3];
    const float* attn_out_w  = (const float*)d_in[4];
    const float* attn_norm_w = (const float*)d_in[5];
    const float* ffn_norm_w  = (const float*)d_in[6];
    const float* ffn_experts = (const float*)d_in[7];
    const float* keys        = (const float*)d_in[8];
    const float* head_probs  = (const float*)d_in[9];
    const float* score_probs = (const float*)d_in[10];
    float* out = (float*)d_out;

    float* ws = (float*)d_ws;
    const size_t MF = 1024 * 1024;
    // Region map (floats), peak 14M floats = 56 MB:
    // qh    [0,1M)    bf16     (gemm_qkv -> flash)
    // khb   [1M,2M)   bf16
    // tmpT  [2M,3M)   bf16     (preprocess -> qkv+tkeys)
    // vhT   [3M,4M)   bf16     (gemm_qkv -> flash, written transposed)
    // xfi   [4M,6M)   f32      (gemm2 -> rmsnorm_dual, moe)
    // xnb   [6M,7M)   bf16     (preprocess -> gemm_qkv); reused: aob (flash->gemm2)
    // woutT [7M,7.5M) bf16     (preprocess -> gemm2)
    // wqkvT [8M,9.5M) bf16     (preprocess -> gemm_qkv); reused: xf [8M,10M) f32
    // kgath [10M,11M) bf16     (qkv+tkeys -> score_gemm)
    // xfb   [11M,12M) bf16     (rmsnorm_dual -> score_gemm)
    // msbufp[12M,14M) f32      (score_gemm -> moe)
    unsigned short* qh    = (unsigned short*)ws;
    unsigned short* khb   = (unsigned short*)(ws + 1 * MF);
    unsigned short* tmpT  = (unsigned short*)(ws + 2 * MF);
    unsigned short* vhT   = (unsigned short*)(ws + 3 * MF);
    float* xfi            = ws + 4 * MF;
    unsigned short* xnb   = (unsigned short*)(ws + 6 * MF);
    unsigned short* aob   = (unsigned short*)(ws + 6 * MF);
    unsigned short* woutT = (unsigned short*)(ws + 7 * MF);
    unsigned short* wqkvT = (unsigned short*)(ws + 8 * MF);
    float* xf             = ws + 8 * MF;
    unsigned short* kgath = (unsigned short*)(ws + 10 * MF);
    unsigned short* xfb   = (unsigned short*)(ws + 11 * MF);
    float* msbufp         = ws + 12 * MF;

    // 1) mega-preprocess: rmsnorm + weight transposes + keys compact
    preprocess_kernel<<<14336, 256, 0, stream>>>(
        x_input, attn_norm_w, xnb, attn_w, wqkvT, attn_out_w, woutT,
        keys, indices, tmpT);

    // 2) fused qkv GEMM (+ keys transpose piggy-backed) -> qh/khb/vhT, kgath
    mfma_gemm_qkv_kernel<<<384 + 2048, 256, 0, stream>>>(
        xnb, wqkvT, qh, khb, vhT, tmpT, kgath);

    // 3) MFMA flash attention (1 barrier/iter, XCD-owned heads) -> aob bf16
    flash_attn_mfma_kernel<<<(S_ / 64) * NH_, 256, 0, stream>>>(qh, khb, vhT, aob);

    // 4) xfi = aob @ attn_out_w + x_input   (MFMA + residual, 128^2 tiles)
    {
        dim3 g(D_ / 128, T_ / 128);
        mfma_gemm_kernel<1><<<g, 256, 0, stream>>>(aob, woutT, x_input, xfi,
                                                   T_, D_, D_);
    }

    // 5) rmsnorm dual: xf fp32 + xfb bf16
    rmsnorm_dual_kernel<<<T_, 256, 0, stream>>>(xfi, ffn_norm_w, xf, xfb);

    // 6) expert score GEMM, split-K x8 -> msbufp partials
    score_gemm_kernel<<<BC_ * 8, 256, 0, stream>>>(xfb, kgath, msbufp);

    // 7) MoE (4 tokens/block, combine weights fused) + final residual
    moe_kernel<<<T_ / 4, 256, 0, stream>>>(xf, xfi, indices, msbufp, scores,
                                           score_probs, head_probs,
                                           ffn_experts, out);
}

// Round 11
// 365.669 us; speedup vs baseline: 1.0376x; 1.0125x over previous
//
#include <hip/hip_runtime.h>
#include <hip/hip_bf16.h>
#include <math.h>

// Problem constants
#define D_   1024
#define HD_  64
#define NH_  16
#define H_   16
#define KH_  8
#define NT_  128      // tokens per chunk (N)
#define E_   4096
#define RE_  4
#define DE_  4
#define ET_  16
#define S_   2048
#define T_   2048
#define BC_  16
#define EPS_ 1e-5f

typedef short s16x8 __attribute__((ext_vector_type(8)));
typedef float f32x4 __attribute__((ext_vector_type(4)));

__device__ __forceinline__ unsigned short f2bf(float f) {
    union { float f; unsigned int u; } v; v.f = f;
    unsigned int r = (v.u + 0x7fffu + ((v.u >> 16) & 1u)) >> 16;  // RNE
    return (unsigned short)r;
}

// async global->LDS, 16B per lane; LDS dest is wave-uniform base + lane*16.
#define GLOAD16(gp, lp) __builtin_amdgcn_global_load_lds(                      \
    (__attribute__((address_space(1))) void*)(gp),                             \
    (__attribute__((address_space(3))) void*)(lp), 16, 0, 0)

// ---------------------------------------------------------------------------
// Mega-preprocess (input-only dependencies), one launch.
// Block order puts the SLOWEST blocks first (keys-compact: 16KB HBM row read
// each) so the dispatch tail is cheap blocks — shorter drain:
//   [0,8192):      keys compact: block (kh,d) reads row keys[kh][d][:]
//                  COALESCED (16KB), LDS-stages, picks 256 indexed cols ->
//                  tmpT[kh][d][pair] bf16.
//   [8192,10240):  rmsnorm(x_input) -> xnb bf16
//   [10240,13312): convt attn_w (1024x3072) -> wqkvT [3072][1024] bf16
//   [13312,14336): convt attn_out_w (1024x1024) -> woutT [1024][1024] bf16
// ---------------------------------------------------------------------------
__global__ __launch_bounds__(256) void preprocess_kernel(
    const float* __restrict__ x, const float* __restrict__ attn_norm_w,
    unsigned short* __restrict__ xnb,
    const float* __restrict__ attn_w, unsigned short* __restrict__ wqkvT,
    const float* __restrict__ attn_out_w, unsigned short* __restrict__ woutT,
    const float* __restrict__ keys, const int* __restrict__ indices,
    unsigned short* __restrict__ tmpT)
{
    __shared__ float tile[32][33];
    __shared__ float sred[4];
    __shared__ float rowbuf[E_];
    int bid = blockIdx.x, tid = threadIdx.x;

    if (bid < 8192) {
        // ---- keys compact: coalesced row read + LDS column pick ----
        int kh = bid >> 10;           // /D_
        int d  = bid & (D_ - 1);
        const float* rowp = keys + ((size_t)kh * D_ + d) * E_;
#pragma unroll
        for (int pass = 0; pass < 4; pass++)
            ((float4*)rowbuf)[tid + pass * 256] =
                ((const float4*)rowp)[tid + pass * 256];
        __syncthreads();
        int idx = indices[tid];       // pair = tid (256 pairs)
        tmpT[((size_t)kh * D_ + d) * 256 + tid] = f2bf(rowbuf[idx]);
    } else if (bid < 10240) {
        // ---- rmsnorm -> bf16 ----
        int row = bid - 8192;
        float4 v = ((const float4*)(x + (size_t)row * D_))[tid];
        float ss = v.x*v.x + v.y*v.y + v.z*v.z + v.w*v.w;
#pragma unroll
        for (int off = 32; off > 0; off >>= 1) ss += __shfl_xor(ss, off);
        if ((tid & 63) == 0) sred[tid >> 6] = ss;
        __syncthreads();
        float tot = sred[0] + sred[1] + sred[2] + sred[3];
        float scale = rsqrtf(tot * (1.0f / D_) + EPS_);
        float4 wv = ((const float4*)attn_norm_w)[tid];
        ushort4 o;
        o.x = f2bf(v.x * scale * wv.x);
        o.y = f2bf(v.y * scale * wv.y);
        o.z = f2bf(v.z * scale * wv.z);
        o.w = f2bf(v.w * scale * wv.w);
        *(ushort4*)(xnb + (size_t)row * D_ + tid * 4) = o;
    } else {
        // ---- convert + transpose weight ----
        const float* src; unsigned short* dst; int R, Ncols, bx, by;
        if (bid < 13312) {
            int cid = bid - 10240;
            src = attn_w; dst = wqkvT; R = D_; Ncols = 3 * D_;
            bx = (cid % 96) * 32; by = (cid / 96) * 32;
        } else {
            int cid = bid - 13312;
            src = attn_out_w; dst = woutT; R = D_; Ncols = D_;
            bx = (cid & 31) * 32; by = (cid >> 5) * 32;
        }
        int tx = tid & 31, ty = tid >> 5;
#pragma unroll
        for (int rr = 0; rr < 32; rr += 8)
            tile[ty + rr][tx] = src[(size_t)(by + ty + rr) * Ncols + bx + tx];
        __syncthreads();
#pragma unroll
        for (int rr = 0; rr < 32; rr += 8)
            dst[(size_t)(bx + ty + rr) * R + by + tx] = f2bf(tile[tx][ty + rr]);
    }
}

// rmsnorm dual: fp32 out + bf16 out
__global__ __launch_bounds__(256) void rmsnorm_dual_kernel(
    const float* __restrict__ x, const float* __restrict__ w,
    float* __restrict__ out, unsigned short* __restrict__ outb)
{
    int row = blockIdx.x, tid = threadIdx.x;
    __shared__ float sred[4];
    float4 v = ((const float4*)(x + (size_t)row * D_))[tid];
    float ss = v.x*v.x + v.y*v.y + v.z*v.z + v.w*v.w;
#pragma unroll
    for (int off = 32; off > 0; off >>= 1) ss += __shfl_xor(ss, off);
    if ((tid & 63) == 0) sred[tid >> 6] = ss;
    __syncthreads();
    float tot = sred[0] + sred[1] + sred[2] + sred[3];
    float scale = rsqrtf(tot * (1.0f / D_) + EPS_);
    float4 wv = ((const float4*)w)[tid];
    float4 o;
    o.x = v.x * scale * wv.x;
    o.y = v.y * scale * wv.y;
    o.z = v.z * scale * wv.z;
    o.w = v.w * scale * wv.w;
    ((float4*)(out + (size_t)row * D_))[tid] = o;
    ushort4 ob;
    ob.x = f2bf(o.x); ob.y = f2bf(o.y); ob.z = f2bf(o.z); ob.w = f2bf(o.w);
    *(ushort4*)(outb + (size_t)row * D_ + tid * 4) = ob;
}

// ---------------------------------------------------------------------------
// MFMA GEMM: C[M,N] fp32 = A[M,K] bf16 @ Bt[N,K] bf16 (+ res fp32)
// ---------------------------------------------------------------------------
template <int WITH_RES>
__global__ __launch_bounds__(256) void mfma_gemm_kernel(
    const unsigned short* __restrict__ A, const unsigned short* __restrict__ Bt,
    const float* __restrict__ res, float* __restrict__ C,
    int M, int N, int K)
{
    __shared__ __align__(16) short As[128][32];
    __shared__ __align__(16) short Bs[128][32];
    int tid = threadIdx.x;
    int wave = tid >> 6, lane = tid & 63;
    int ml = lane & 15, q = lane >> 4;
    int wr = wave >> 1, wc = wave & 1;
    int bm = blockIdx.y * 128, bn = blockIdx.x * 128;
    int srow = tid >> 2;           // 0..63
    int scol = (tid & 3) * 8;      // shorts

    f32x4 acc[4][4];
#pragma unroll
    for (int i = 0; i < 4; i++)
#pragma unroll
        for (int j = 0; j < 4; j++) acc[i][j] = (f32x4){0.f, 0.f, 0.f, 0.f};

    const unsigned short* Ap = A  + (size_t)(bm + srow) * K + scol;
    const unsigned short* Bp = Bt + (size_t)(bn + srow) * K + scol;
    short* ldsA0 = &As[wave * 16][0];
    short* ldsA1 = &As[64 + wave * 16][0];
    short* ldsB0 = &Bs[wave * 16][0];
    short* ldsB1 = &Bs[64 + wave * 16][0];

    for (int k0 = 0; k0 < K; k0 += 32) {
        __syncthreads();
        GLOAD16(Ap + k0, ldsA0);
        GLOAD16(Ap + (size_t)64 * K + k0, ldsA1);
        GLOAD16(Bp + k0, ldsB0);
        GLOAD16(Bp + (size_t)64 * K + k0, ldsB1);
        __syncthreads();

        s16x8 af[4], bf[4];
#pragma unroll
        for (int i = 0; i < 4; i++)
            af[i] = *(const s16x8*)(&As[wr * 64 + i * 16 + ml][q * 8]);
#pragma unroll
        for (int j = 0; j < 4; j++)
            bf[j] = *(const s16x8*)(&Bs[wc * 64 + j * 16 + ml][q * 8]);
#pragma unroll
        for (int i = 0; i < 4; i++)
#pragma unroll
            for (int j = 0; j < 4; j++)
                acc[i][j] = __builtin_amdgcn_mfma_f32_16x16x32_bf16(
                    af[i], bf[j], acc[i][j], 0, 0, 0);
    }

#pragma unroll
    for (int i = 0; i < 4; i++) {
#pragma unroll
        for (int j = 0; j < 4; j++) {
            int col = bn + wc * 64 + j * 16 + ml;
#pragma unroll
            for (int r = 0; r < 4; r++) {
                int row = bm + wr * 64 + i * 16 + q * 4 + r;
                float v = acc[i][j][r];
                if (WITH_RES) v += res[(size_t)row * N + col];
                C[(size_t)row * N + col] = v;
            }
        }
    }
}

// ---------------------------------------------------------------------------
// Fused QKV GEMM + keys transpose (independent work, one launch):
//   bid <  384:  qkv GEMM block. Epilogue l2norm + rope + split; V written
//                directly transposed (vhT[h][d][s]). RoPE angles advance by
//                Givens rotation: 6 sincosf per lane (base, step16, step1 per
//                freq) instead of 32 — rotation drift ~1e-7 << bf16 rounding.
//   bid >= 384:  keys transpose tile: tmpT [kh][d][pair] ->
//                kgath[(pair>>4)*128+(pair&15)*8+kh][d].
// ---------------------------------------------------------------------------
__global__ __launch_bounds__(256) void mfma_gemm_qkv_kernel(
    const unsigned short* __restrict__ A, const unsigned short* __restrict__ Bt,
    unsigned short* __restrict__ qh, unsigned short* __restrict__ khb,
    unsigned short* __restrict__ vhT,
    const unsigned short* __restrict__ tmpT, unsigned short* __restrict__ kgath)
{
    const int K = D_;
    __shared__ __align__(16) short As[128][32];
    __shared__ __align__(16) short Bs[128][32];
    __shared__ unsigned short ttile[32][34];
    int bid = blockIdx.x;
    int tid = threadIdx.x;

    if (bid >= 384) {
        // ---- keys transpose tile ----
        int id = bid - 384;           // 0..2047
        int p0 = (id & 7) * 32;       // pair tile (8)
        int d0 = ((id >> 3) & 31) * 32;  // d tile (32)
        int kh = id >> 8;             // (8)
        int tx = tid & 31, ty = tid >> 5;
#pragma unroll
        for (int rr = 0; rr < 32; rr += 8)
            ttile[ty + rr][tx] =
                tmpT[((size_t)kh * D_ + d0 + ty + rr) * 256 + p0 + tx];
        __syncthreads();
#pragma unroll
        for (int rr = 0; rr < 32; rr += 8) {
            int p = p0 + ty + rr;
            int n = (p >> 4) * 128 + (p & 15) * 8 + kh;
            kgath[(size_t)n * D_ + d0 + tx] = ttile[tx][ty + rr];
        }
        return;
    }

    int gx = bid % 24, gy = bid / 24;
    int wave = tid >> 6, lane = tid & 63;
    int ml = lane & 15, q = lane >> 4;
    int wr = wave >> 1, wc = wave & 1;
    int bm = gy * 128, bn = gx * 128;
    int srow = tid >> 2;
    int scol = (tid & 3) * 8;

    f32x4 acc[4][4];
#pragma unroll
    for (int i = 0; i < 4; i++)
#pragma unroll
        for (int j = 0; j < 4; j++) acc[i][j] = (f32x4){0.f, 0.f, 0.f, 0.f};

    const unsigned short* Ap = A  + (size_t)(bm + srow) * K + scol;
    const unsigned short* Bp = Bt + (size_t)(bn + srow) * K + scol;
    short* ldsA0 = &As[wave * 16][0];
    short* ldsA1 = &As[64 + wave * 16][0];
    short* ldsB0 = &Bs[wave * 16][0];
    short* ldsB1 = &Bs[64 + wave * 16][0];

    for (int k0 = 0; k0 < K; k0 += 32) {
        __syncthreads();
        GLOAD16(Ap + k0, ldsA0);
        GLOAD16(Ap + (size_t)64 * K + k0, ldsA1);
        GLOAD16(Bp + k0, ldsB0);
        GLOAD16(Bp + (size_t)64 * K + k0, ldsB1);
        __syncthreads();

        s16x8 af[4], bf[4];
#pragma unroll
        for (int i = 0; i < 4; i++)
            af[i] = *(const s16x8*)(&As[wr * 64 + i * 16 + ml][q * 8]);
#pragma unroll
        for (int j = 0; j < 4; j++)
            bf[j] = *(const s16x8*)(&Bs[wc * 64 + j * 16 + ml][q * 8]);
#pragma unroll
        for (int i = 0; i < 4; i++)
#pragma unroll
            for (int j = 0; j < 4; j++)
                acc[i][j] = __builtin_amdgcn_mfma_f32_16x16x32_bf16(
                    af[i], bf[j], acc[i][j], 0, 0, 0);
    }

    // ---- epilogue: l2norm + rope + bf16 split write ----
    int sel = gx >> 3;                  // 0:q 1:k 2:v
    int h = ((gx & 7) << 1) + wc;       // head for this wave
    float qscale = (sel == 0) ? 0.125f : 1.0f;  // fold 1/sqrt(64) into q
    float if0 = exp2f((float)ml * (-13.287712379549449f / 32.0f));
    float if1 = exp2f((float)(16 + ml) * (-13.287712379549449f / 32.0f));

    // hoisted sincos (6 calls) + per-row Givens rotations
    float bc0 = 0.f, bs0 = 0.f, bc1 = 0.f, bs1 = 0.f;
    float c16c0 = 0.f, c16s0 = 0.f, c16c1 = 0.f, c16s1 = 0.f;
    float c1c0 = 0.f, c1s0 = 0.f, c1c1 = 0.f, c1s1 = 0.f;
    if (sel < 2) {
        float r0f = (float)(bm + wr * 64 + q * 4);
        sincosf(r0f * if0, &bs0, &bc0);
        sincosf(r0f * if1, &bs1, &bc1);
        sincosf(16.0f * if0, &c16s0, &c16c0);
        sincosf(16.0f * if1, &c16s1, &c16c1);
        sincosf(if0, &c1s0, &c1c0);
        sincosf(if1, &c1s1, &c1c1);
    }

#pragma unroll
    for (int i = 0; i < 4; i++) {
        float rc0 = bc0, rs0 = bs0, rc1 = bc1, rs1 = bs1;
#pragma unroll
        for (int r = 0; r < 4; r++) {
            int row = bm + wr * 64 + i * 16 + q * 4 + r;
            float v0 = acc[i][0][r], v1 = acc[i][1][r];
            float v2 = acc[i][2][r], v3 = acc[i][3][r];
            if (sel < 2) {
                float ss = v0*v0 + v1*v1 + v2*v2 + v3*v3;
#pragma unroll
                for (int off = 1; off < 16; off <<= 1)
                    ss += __shfl_xor(ss, off);
                float inv = qscale / fmaxf(sqrtf(ss), EPS_);
                v0 *= inv; v1 *= inv; v2 *= inv; v3 *= inv;
                float cs0 = rc0, sn0 = rs0, cs1 = rc1, sn1 = rs1;
                float o0 = v0 * cs0 + v2 * sn0;
                float o2 = v2 * cs0 - v0 * sn0;
                float o1 = v1 * cs1 + v3 * sn1;
                float o3 = v3 * cs1 - v1 * sn1;
                v0 = o0; v1 = o1; v2 = o2; v3 = o3;
                // advance angles by one row
                float t0 = rc0 * c1c0 - rs0 * c1s0;
                rs0 = rs0 * c1c0 + rc0 * c1s0; rc0 = t0;
                float t1 = rc1 * c1c1 - rs1 * c1s1;
                rs1 = rs1 * c1c1 + rc1 * c1s1; rc1 = t1;
                unsigned short* dst = (sel == 0) ? qh : khb;
                size_t base = ((size_t)h * S_ + row) * HD_;
                dst[base +      ml] = f2bf(v0);
                dst[base + 16 + ml] = f2bf(v1);
                dst[base + 32 + ml] = f2bf(v2);
                dst[base + 48 + ml] = f2bf(v3);
            } else {
                // V: write transposed vhT[h][d][row], d = k*16 + ml
                size_t base = ((size_t)h * HD_ + ml) * S_ + row;
                vhT[base            ] = f2bf(v0);
                vhT[base + 16 * S_  ] = f2bf(v1);
                vhT[base + 32 * S_  ] = f2bf(v2);
                vhT[base + 48 * S_  ] = f2bf(v3);
            }
        }
        if (sel < 2) {
            // advance base angles by 16 rows
            float t0 = bc0 * c16c0 - bs0 * c16s0;
            bs0 = bs0 * c16c0 + bc0 * c16s0; bc0 = t0;
            float t1 = bc1 * c16c1 - bs1 * c16s1;
            bs1 = bs1 * c16c1 + bc1 * c16s1; bc1 = t1;
        }
    }
}

// ---------------------------------------------------------------------------
// MFMA bf16 flash attention, double-buffered LDS, ONE barrier per k-iter.
// XCD-aware mapping: bid = (xcd = bid&7, j = bid>>3); head h = 2*xcd + (j&1)
// so each XCD owns exactly 2 heads -> K + V^T (1 MB) stays L2-resident.
// Heavy/light pairing preserved: j<32 gives t=0..15, j>=32 gives t=31..16.
// Bounded-score softmax (|s|<=0.125 by Cauchy-Schwarz, no online max).
// ---------------------------------------------------------------------------
#define FS 72   // shorts per LDS row (pad: 144B rows -> 2-way banks, free)
__global__ __launch_bounds__(256) void flash_attn_mfma_kernel(
    const unsigned short* __restrict__ qh, const unsigned short* __restrict__ khb,
    const unsigned short* __restrict__ vhT, unsigned short* __restrict__ aob)
{
    __shared__ __align__(16) short Ks[2][64][FS];
    __shared__ __align__(16) short Vs[2][64][FS];   // [buf][d][token]
    __shared__ __align__(16) short Ps[4][16][FS];   // per-wave scratch
    int b = blockIdx.x;
    int xcd = b & 7, j = b >> 3;
    int h = 2 * xcd + (j & 1);
    int pp = (j >> 1) & 15;
    int t = (j >> 5) ? (31 - pp) : pp;
    int tid = threadIdx.x;
    int wq = tid >> 6;
    int lane = tid & 63;
    int ml = lane & 15, quad = lane >> 4;
    int srow = tid >> 2;          // 0..63
    int sc = (tid & 3) * 16;      // 0,16,32,48 (shorts)
    const unsigned short* Qb = qh  + (size_t)h * S_ * HD_;
    const unsigned short* Kb = khb + (size_t)h * S_ * HD_;
    const unsigned short* Vt = vhT + (size_t)h * HD_ * S_;

    int q0 = t * 64;
    int qrow = q0 + wq * 16 + ml;
    s16x8 aq0 = *(const s16x8*)(Qb + (size_t)qrow * HD_ + quad * 8);
    s16x8 aq1 = *(const s16x8*)(Qb + (size_t)qrow * HD_ + 32 + quad * 8);

    float ps[4];                  // per-lane partial row sums
    f32x4 o[4];
#pragma unroll
    for (int r = 0; r < 4; r++) ps[r] = 0.f;
#pragma unroll
    for (int nb = 0; nb < 4; nb++) o[nb] = (f32x4){0.f, 0.f, 0.f, 0.f};

    int4 kr0, kr1, vr0, vr1;      // staging registers
    // prologue: tile 0 -> buf 0 (visibility covered by iter-0 top barrier)
    {
        const unsigned short* kp = Kb + (size_t)srow * HD_ + sc;
        kr0 = *(const int4*)kp; kr1 = *(const int4*)(kp + 8);
        const unsigned short* vp = Vt + (size_t)srow * S_ + sc;
        vr0 = *(const int4*)vp; vr1 = *(const int4*)(vp + 8);
        *(int4*)(&Ks[0][srow][sc]) = kr0; *(int4*)(&Ks[0][srow][sc + 8]) = kr1;
        *(int4*)(&Vs[0][srow][sc]) = vr0; *(int4*)(&Vs[0][srow][sc + 8]) = vr1;
    }

    for (int kt = 0; kt <= t; kt++) {
        int k0 = kt * 64;
        int cur = kt & 1;
        // issue next tile's global loads early (latency hides under compute)
        if (kt < t) {
            const unsigned short* kp = Kb + (size_t)(k0 + 64 + srow) * HD_ + sc;
            kr0 = *(const int4*)kp; kr1 = *(const int4*)(kp + 8);
            const unsigned short* vp = Vt + (size_t)srow * S_ + k0 + 64 + sc;
            vr0 = *(const int4*)vp; vr1 = *(const int4*)(vp + 8);
        }
        __syncthreads();           // single barrier per iteration

        f32x4 s[4];
#pragma unroll
        for (int nb = 0; nb < 4; nb++) s[nb] = (f32x4){0.f, 0.f, 0.f, 0.f};
        __builtin_amdgcn_s_setprio(1);
#pragma unroll
        for (int nb = 0; nb < 4; nb++) {
            s16x8 b0 = *(const s16x8*)(&Ks[cur][nb * 16 + ml][quad * 8]);
            s16x8 b1 = *(const s16x8*)(&Ks[cur][nb * 16 + ml][32 + quad * 8]);
            s[nb] = __builtin_amdgcn_mfma_f32_16x16x32_bf16(aq0, b0, s[nb], 0, 0, 0);
            s[nb] = __builtin_amdgcn_mfma_f32_16x16x32_bf16(aq1, b1, s[nb], 0, 0, 0);
        }
        __builtin_amdgcn_s_setprio(0);

        // P = exp(S) (bounded, no max needed); masked -> 0; per-lane row sums
#pragma unroll
        for (int nb = 0; nb < 4; nb++)
#pragma unroll
            for (int r = 0; r < 4; r++) {
                float pe = __expf(s[nb][r]);
                if (kt == t && (nb * 16 + ml) > (wq * 16 + quad * 4 + r))
                    pe = 0.f;
                ps[r] += pe;
                Ps[wq][quad * 4 + r][nb * 16 + ml] = (short)f2bf(pe);
            }

        s16x8 ap0 = *(const s16x8*)(&Ps[wq][ml][quad * 8]);
        s16x8 ap1 = *(const s16x8*)(&Ps[wq][ml][32 + quad * 8]);
        __builtin_amdgcn_s_setprio(1);
#pragma unroll
        for (int nb = 0; nb < 4; nb++) {
            s16x8 b0 = *(const s16x8*)(&Vs[cur][nb * 16 + ml][quad * 8]);
            s16x8 b1 = *(const s16x8*)(&Vs[cur][nb * 16 + ml][32 + quad * 8]);
            o[nb] = __builtin_amdgcn_mfma_f32_16x16x32_bf16(ap0, b0, o[nb], 0, 0, 0);
            o[nb] = __builtin_amdgcn_mfma_f32_16x16x32_bf16(ap1, b1, o[nb], 0, 0, 0);
        }
        __builtin_amdgcn_s_setprio(0);

        // write next tile into the other buffer; next iter's barrier covers it
        if (kt < t) {
            *(int4*)(&Ks[cur ^ 1][srow][sc])     = kr0;
            *(int4*)(&Ks[cur ^ 1][srow][sc + 8]) = kr1;
            *(int4*)(&Vs[cur ^ 1][srow][sc])     = vr0;
            *(int4*)(&Vs[cur ^ 1][srow][sc + 8]) = vr1;
        }
    }

    // final: reduce row sums over the 16 ml lanes (same quad), normalize.
#pragma unroll
    for (int r = 0; r < 4; r++) {
        float l = ps[r];
#pragma unroll
        for (int off = 1; off < 16; off <<= 1)
            l += __shfl_xor(l, off);
        float inv = 1.0f / l;
        int row = q0 + wq * 16 + quad * 4 + r;
#pragma unroll
        for (int nb = 0; nb < 4; nb++)
            aob[(size_t)row * D_ + h * HD_ + nb * 16 + ml] =
                f2bf(o[nb][r] * inv);
    }
}

// ---------------------------------------------------------------------------
// expert score GEMM, split-K x8: block = (chunk c, k-slice sk).
// ---------------------------------------------------------------------------
__global__ __launch_bounds__(256) void score_gemm_kernel(
    const unsigned short* __restrict__ xfb, const unsigned short* __restrict__ kgath,
    float* __restrict__ msbufp)
{
    __shared__ __align__(16) short As[128][32];
    __shared__ __align__(16) short Bs[128][32];
    int c  = blockIdx.x >> 3;
    int sk = blockIdx.x & 7;
    const unsigned short* A  = xfb   + (size_t)c * 128 * D_ + sk * 128;
    const unsigned short* Bt = kgath + (size_t)c * 128 * D_ + sk * 128;
    int tid = threadIdx.x;
    int wave = tid >> 6, lane = tid & 63;
    int ml = lane & 15, q = lane >> 4;
    int wr = wave >> 1, wc = wave & 1;
    int srow = tid >> 2;
    int scol = (tid & 3) * 8;

    f32x4 acc[4][4];
#pragma unroll
    for (int i = 0; i < 4; i++)
#pragma unroll
        for (int j = 0; j < 4; j++) acc[i][j] = (f32x4){0.f, 0.f, 0.f, 0.f};

    const unsigned short* Ap = A  + (size_t)srow * D_ + scol;
    const unsigned short* Bp = Bt + (size_t)srow * D_ + scol;
    short* ldsA0 = &As[wave * 16][0];
    short* ldsA1 = &As[64 + wave * 16][0];
    short* ldsB0 = &Bs[wave * 16][0];
    short* ldsB1 = &Bs[64 + wave * 16][0];

    for (int k0 = 0; k0 < 128; k0 += 32) {
        __syncthreads();
        GLOAD16(Ap + k0, ldsA0);
        GLOAD16(Ap + (size_t)64 * D_ + k0, ldsA1);
        GLOAD16(Bp + k0, ldsB0);
        GLOAD16(Bp + (size_t)64 * D_ + k0, ldsB1);
        __syncthreads();

        s16x8 af[4], bf[4];
#pragma unroll
        for (int i = 0; i < 4; i++)
            af[i] = *(const s16x8*)(&As[wr * 64 + i * 16 + ml][q * 8]);
#pragma unroll
        for (int j = 0; j < 4; j++)
            bf[j] = *(const s16x8*)(&Bs[wc * 64 + j * 16 + ml][q * 8]);
#pragma unroll
        for (int i = 0; i < 4; i++)
#pragma unroll
            for (int j = 0; j < 4; j++)
                acc[i][j] = __builtin_amdgcn_mfma_f32_16x16x32_bf16(
                    af[i], bf[j], acc[i][j], 0, 0, 0);
    }

    float* out = msbufp + (size_t)blockIdx.x * 128 * 128;
#pragma unroll
    for (int i = 0; i < 4; i++)
#pragma unroll
        for (int j = 0; j < 4; j++) {
            int col = wc * 64 + j * 16 + ml;
#pragma unroll
            for (int r = 0; r < 4; r++) {
                int row = wr * 64 + i * 16 + q * 4 + r;
                out[(size_t)row * 128 + col] = acc[i][j][r];
            }
        }
}

// ---------------------------------------------------------------------------
// MoE with rank-1 experts + fused combine weights; 4 tokens per block.
// ---------------------------------------------------------------------------
__global__ __launch_bounds__(256) void moe_kernel(
    const float* __restrict__ xf, const float* __restrict__ xfi,
    const int* __restrict__ indices, const float* __restrict__ msbufp,
    const float* __restrict__ scores,
    const float* __restrict__ score_probs, const float* __restrict__ head_probs,
    const float* __restrict__ experts, float* __restrict__ out)
{
    int g = blockIdx.x, tid = threadIdx.x;
    int c = g >> 5;
    int t0 = c * NT_ + (g & 31) * 4;
    __shared__ int sidx[ET_];
    __shared__ float sw[4][ET_];
    __shared__ float sact[4][ET_];
    __shared__ float sx[4][D_];
    if (tid < ET_) sidx[tid] = indices[c * ET_ + tid];
#pragma unroll
    for (int tt = 0; tt < 4; tt++)
        ((float4*)sx[tt])[tid] =
            ((const float4*)(xf + (size_t)(t0 + tt) * D_))[tid];
    // ---- phase A: combine weights; thread = (e = tid>>4, hh = tid&15) ----
    {
        int e = tid >> 4, hh = tid & 15;
        int idxe = indices[c * ET_ + e];
        int rr = e >> 2;   // e / DE_
        float sp0 = score_probs[((size_t)rr * E_ + idxe) * H_ + hh];
        float sp1 = score_probs[((size_t)(RE_ + rr) * E_ + idxe) * H_ + hh];
        float hp  = head_probs[((size_t)rr * E_ + idxe) * H_ + hh];
#pragma unroll
        for (int tt = 0; tt < 4; tt++) {
            int t = t0 + tt;
            int trow = t & 127;
            const float* mp = msbufp + ((size_t)(c * 8) * 128 + trow) * 128
                                     + e * 8 + (hh >> 1);
            float ms = 0.f;
#pragma unroll
            for (int sck = 0; sck < 8; sck++)
                ms += mp[(size_t)sck * 128 * 128];
            float scv = scores[(size_t)t * (ET_ * H_) + tid];
            float z = sp0 * ms + sp1 * scv;
            float term = hp / (1.0f + __expf(-z));
#pragma unroll
            for (int off = 1; off < 16; off <<= 1)
                term += __shfl_xor(term, off);
            if (hh == 0) sw[tt][e] = term;
        }
    }
    __syncthreads();   // sx, sw, sidx ready

    // ---- phase B: wave wv computes h0/h1/act for experts 4wv..4wv+3 ----
    int wv = tid >> 6, lane = tid & 63;
#pragma unroll
    for (int ee = 0; ee < 4; ee++) {
        int e = wv * 4 + ee;
        int idx = sidx[e];
        size_t base = (size_t)idx * D_;
        float p0[4] = {0.f, 0.f, 0.f, 0.f};
        float p1[4] = {0.f, 0.f, 0.f, 0.f};
#pragma unroll
        for (int rr = 0; rr < 4; rr++) {
            int dd = rr * 256 + lane * 4;
            float4 w0 = *(const float4*)(experts + base + dd);
            float4 w1 = *(const float4*)(experts + (size_t)E_ * D_ + base + dd);
#pragma unroll
            for (int tt = 0; tt < 4; tt++) {
                float4 xr = *(const float4*)(&sx[tt][dd]);
                p0[tt] += xr.x*w0.x + xr.y*w0.y + xr.z*w0.z + xr.w*w0.w;
                p1[tt] += xr.x*w1.x + xr.y*w1.y + xr.z*w1.z + xr.w*w1.w;
            }
        }
#pragma unroll
        for (int tt = 0; tt < 4; tt++) {
#pragma unroll
            for (int off = 32; off > 0; off >>= 1) {
                p0[tt] += __shfl_xor(p0[tt], off);
                p1[tt] += __shfl_xor(p1[tt], off);
            }
        }
        if (lane == 0) {
#pragma unroll
            for (int tt = 0; tt < 4; tt++)
                sact[tt][e] = p0[tt] / (1.0f + __expf(-p0[tt])) * p1[tt]
                              * sw[tt][e];
        }
    }
    __syncthreads();   // sact ready

    // ---- phase C: accumulate w2, amortized over 4 tokens ----
    float4 a0 = {0,0,0,0}, a1 = {0,0,0,0}, a2 = {0,0,0,0}, a3 = {0,0,0,0};
    const float* w2base = experts + (size_t)2 * E_ * D_;
#pragma unroll
    for (int e = 0; e < ET_; e++) {
        float4 w2 = *(const float4*)(w2base + (size_t)sidx[e] * D_ + tid * 4);
        float c0 = sact[0][e], c1 = sact[1][e], c2 = sact[2][e], c3 = sact[3][e];
        a0.x += c0 * w2.x; a0.y += c0 * w2.y; a0.z += c0 * w2.z; a0.w += c0 * w2.w;
        a1.x += c1 * w2.x; a1.y += c1 * w2.y; a1.z += c1 * w2.z; a1.w += c1 * w2.w;
        a2.x += c2 * w2.x; a2.y += c2 * w2.y; a2.z += c2 * w2.z; a2.w += c2 * w2.w;
        a3.x += c3 * w2.x; a3.y += c3 * w2.y; a3.z += c3 * w2.z; a3.w += c3 * w2.w;
    }
#pragma unroll
    for (int tt = 0; tt < 4; tt++) {
        float4 av = (tt == 0) ? a0 : (tt == 1) ? a1 : (tt == 2) ? a2 : a3;
        size_t o = (size_t)(t0 + tt) * D_ + tid * 4;
        float4 rv = *(const float4*)(xfi + o);
        float4 ov;
        ov.x = av.x + rv.x;
        ov.y = av.y + rv.y;
        ov.z = av.z + rv.z;
        ov.w = av.w + rv.w;
        *(float4*)(out + o) = ov;
    }
}

// ---------------------------------------------------------------------------
extern "C" void kernel_launch(void* const* d_in, const int* in_sizes, int n_in,
                              void* d_out, int out_size, void* d_ws, size_t ws_size,
                              hipStream_t stream)
{
    (void)in_sizes; (void)n_in; (void)out_size; (void)ws_size;
    const float* x_input     = (const float*)d_in[0];
    const int*   indices     = (const int*)d_in[1];
    const float* scores      = (const float*)d_in[2];
    const float* attn_w      = (const float*)d_in[3];
    const float* attn_out_w  = (const float*)d_in[4];
    const float* attn_norm_w = (const float*)d_in[5];
    const float* ffn_norm_w  = (const float*)d_in[6];
    const float* ffn_experts = (const float*)d_in[7];
    const float* keys        = (const float*)d_in[8];
    const float* head_probs  = (const float*)d_in[9];
    const float* score_probs = (const float*)d_in[10];
    float* out = (float*)d_out;

    float* ws = (float*)d_ws;
    const size_t MF = 1024 * 1024;
    // Region map (floats), peak 14M floats = 56 MB:
    // qh    [0,1M)    bf16     (gemm_qkv -> flash)
    // khb   [1M,2M)   bf16
    // tmpT  [2M,3M)   bf16     (preprocess -> qkv+tkeys)
    // vhT   [3M,4M)   bf16     (gemm_qkv -> flash, written transposed)
    // xfi   [4M,6M)   f32      (gemm2 -> rmsnorm_dual, moe)
    // xnb   [6M,7M)   bf16     (preprocess -> gemm_qkv); reused: aob (flash->gemm2)
    // woutT [7M,7.5M) bf16     (preprocess -> gemm2)
    // wqkvT [8M,9.5M) bf16     (preprocess -> gemm_qkv); reused: xf [8M,10M) f32
    // kgath [10M,11M) bf16     (qkv+tkeys -> score_gemm)
    // xfb   [11M,12M) bf16     (rmsnorm_dual -> score_gemm)
    // msbufp[12M,14M) f32      (score_gemm -> moe)
    unsigned short* qh    = (unsigned short*)ws;
    unsigned short* khb   = (unsigned short*)(ws + 1 * MF);
    unsigned short* tmpT  = (unsigned short*)(ws + 2 * MF);
    unsigned short* vhT   = (unsigned short*)(ws + 3 * MF);
    float* xfi            = ws + 4 * MF;
    unsigned short* xnb   = (unsigned short*)(ws + 6 * MF);
    unsigned short* aob   = (unsigned short*)(ws + 6 * MF);
    unsigned short* woutT = (unsigned short*)(ws + 7 * MF);
    unsigned short* wqkvT = (unsigned short*)(ws + 8 * MF);
    float* xf             = ws + 8 * MF;
    unsigned short* kgath = (unsigned short*)(ws + 10 * MF);
    unsigned short* xfb   = (unsigned short*)(ws + 11 * MF);
    float* msbufp         = ws + 12 * MF;

    // 1) mega-preprocess: keys compact (slow, first) + rmsnorm + transposes
    preprocess_kernel<<<14336, 256, 0, stream>>>(
        x_input, attn_norm_w, xnb, attn_w, wqkvT, attn_out_w, woutT,
        keys, indices, tmpT);

    // 2) fused qkv GEMM (+ keys transpose piggy-backed) -> qh/khb/vhT, kgath
    mfma_gemm_qkv_kernel<<<384 + 2048, 256, 0, stream>>>(
        xnb, wqkvT, qh, khb, vhT, tmpT, kgath);

    // 3) MFMA flash attention (1 barrier/iter, XCD-owned heads) -> aob bf16
    flash_attn_mfma_kernel<<<(S_ / 64) * NH_, 256, 0, stream>>>(qh, khb, vhT, aob);

    // 4) xfi = aob @ attn_out_w + x_input   (MFMA + residual, 128^2 tiles)
    {
        dim3 g(D_ / 128, T_ / 128);
        mfma_gemm_kernel<1><<<g, 256, 0, stream>>>(aob, woutT, x_input, xfi,
                                                   T_, D_, D_);
    }

    // 5) rmsnorm dual: xf fp32 + xfb bf16
    rmsnorm_dual_kernel<<<T_, 256, 0, stream>>>(xfi, ffn_norm_w, xf, xfb);

    // 6) expert score GEMM, split-K x8 -> msbufp partials
    score_gemm_kernel<<<BC_ * 8, 256, 0, stream>>>(xfb, kgath, msbufp);

    // 7) MoE (4 tokens/block, combine weights fused) + final residual
    moe_kernel<<<T_ / 4, 256, 0, stream>>>(xf, xfi, indices, msbufp, scores,
                                           score_probs, head_probs,
                                           ffn_experts, out);
}